// Round 6
// baseline (363.953 us; speedup 1.0000x reference)
//
#include <hip/hip_runtime.h>
#include <hip/hip_bf16.h>
#include <cstdint>
#include <cstddef>

#define NNODES 50000
#define NEDGES 500000
#define ETOT   (NEDGES + NNODES)

typedef __attribute__((ext_vector_type(8))) short short8;
typedef __attribute__((ext_vector_type(8))) unsigned short ushort8v;
typedef __attribute__((ext_vector_type(4))) float floatx4;
typedef __attribute__((ext_vector_type(4))) unsigned short ushort4v;

__device__ __forceinline__ unsigned short f2bf(float f) {
    union { __hip_bfloat16 h; unsigned short u; } cv;
    cv.h = __float2bfloat16(f);
    return cv.u;
}
__device__ __forceinline__ float bf2f(unsigned short u) {
    union { unsigned int i; float f; } cv;
    cv.i = ((unsigned int)u) << 16;
    return cv.f;
}

// ================= bf16 MFMA GEMM: C/Cb = op(A @ Bt^T + bias) =================
#define GBM 128
#define GBN 64
#define GBK 32

__global__ __launch_bounds__(256, 4) void gemm_mfma(
    const unsigned short* __restrict__ A, int lda,
    const unsigned short* __restrict__ Bt,
    float* __restrict__ C,
    unsigned short* __restrict__ Cb, int ldc,
    const float* __restrict__ bias,
    float* __restrict__ colsum, float* __restrict__ colsq,
    int M, int N, int K, int do_relu)
{
    __shared__ __attribute__((aligned(16))) unsigned short Alds[GBM * GBK];
    __shared__ __attribute__((aligned(16))) unsigned short Blds[GBN * GBK];
    __shared__ float scol[GBN], sqcol[GBN];

    int tid = threadIdx.x;
    int wave = tid >> 6, lane = tid & 63;
    int row0 = blockIdx.y * GBM;
    int col0 = blockIdx.x * GBN;
    int m = lane & 15, q = lane >> 4;

    floatx4 acc[2][4] = {};

    for (int k0 = 0; k0 < K; k0 += GBK) {
        #pragma unroll
        for (int i = 0; i < 2; ++i) {
            int c = tid + i * 256;
            int r = c >> 2, off = (c & 3) * 8;
            int gr = row0 + r;
            short8 v = {};
            if (gr < M) v = *(const short8*)(A + (size_t)gr * lda + k0 + off);
            *(short8*)(Alds + r * GBK + off) = v;
        }
        {
            int r = tid >> 2, off = (tid & 3) * 8;
            short8 v = *(const short8*)(Bt + (size_t)(col0 + r) * K + k0 + off);
            *(short8*)(Blds + r * GBK + off) = v;
        }
        __syncthreads();

        short8 a0 = *(const short8*)(Alds + (wave * 32 + m) * GBK + q * 8);
        short8 a1 = *(const short8*)(Alds + (wave * 32 + 16 + m) * GBK + q * 8);
        #pragma unroll
        for (int ct = 0; ct < 4; ++ct) {
            short8 b = *(const short8*)(Blds + (ct * 16 + m) * GBK + q * 8);
            acc[0][ct] = __builtin_amdgcn_mfma_f32_16x16x32_bf16(a0, b, acc[0][ct], 0, 0, 0);
            acc[1][ct] = __builtin_amdgcn_mfma_f32_16x16x32_bf16(a1, b, acc[1][ct], 0, 0, 0);
        }
        __syncthreads();
    }

    float ps[4] = {}, pq[4] = {};
    #pragma unroll
    for (int rt = 0; rt < 2; ++rt) {
        #pragma unroll
        for (int r = 0; r < 4; ++r) {
            int gr = row0 + wave * 32 + rt * 16 + q * 4 + r;
            #pragma unroll
            for (int ct = 0; ct < 4; ++ct) {
                int gc = col0 + ct * 16 + m;
                float v = acc[rt][ct][r];
                if (gc < N) {
                    float vb = v;
                    if (bias != nullptr) vb += bias[gc];
                    if (do_relu) vb = fmaxf(vb, 0.f);
                    if (gr < M) {
                        if (C  != nullptr) C[(size_t)gr * ldc + gc] = vb;
                        if (Cb != nullptr) Cb[(size_t)gr * ldc + gc] = f2bf(vb);
                        ps[ct] += vb; pq[ct] += vb * vb;
                    }
                }
            }
        }
    }
    if (colsum != nullptr) {
        if (tid < GBN) { scol[tid] = 0.f; sqcol[tid] = 0.f; }
        __syncthreads();
        #pragma unroll
        for (int ct = 0; ct < 4; ++ct) {
            atomicAdd(&scol[ct * 16 + m], ps[ct]);
            atomicAdd(&sqcol[ct * 16 + m], pq[ct]);
        }
        __syncthreads();
        if (tid < GBN) {
            int gc = col0 + tid;
            if (gc < N) {
                atomicAdd(&colsum[gc], scol[tid]);
                atomicAdd(&colsq[gc], sqcol[tid]);
            }
        }
    }
}

// ================= fold att vectors through W1/W2 + cast weights (merged) ======
__global__ __launch_bounds__(256) void fold_cast(
    const float* __restrict__ W1, const float* __restrict__ as1v, const float* __restrict__ ad1v,
    const float* __restrict__ W2, const float* __restrict__ as2v, const float* __restrict__ ad2v,
    const float* __restrict__ Wl,
    float* __restrict__ U1, float* __restrict__ U2,
    unsigned short* __restrict__ W1t, unsigned short* __restrict__ W2t,
    unsigned short* __restrict__ Wlt)
{
    if (blockIdx.x < 64) {
        int g = threadIdx.x >> 5, l = threadIdx.x & 31;
        int task = blockIdx.x * 8 + g;   // 0..511
        float ss = 0.f, sd = 0.f;
        if (task < 256) {
            int d = task & 127, h = task >> 7;
            const float4 wv = *(const float4*)(W1 + d * 256 + h * 128 + l * 4);
            const float4 av = *(const float4*)(as1v + h * 128 + l * 4);
            const float4 bv = *(const float4*)(ad1v + h * 128 + l * 4);
            ss = wv.x * av.x + wv.y * av.y + wv.z * av.z + wv.w * av.w;
            sd = wv.x * bv.x + wv.y * bv.y + wv.z * bv.z + wv.w * bv.w;
        } else {
            int k = task - 256;
            const float4 wv = *(const float4*)(W2 + (size_t)k * 128 + l * 4);
            const float4 av = *(const float4*)(as2v + l * 4);
            const float4 bv = *(const float4*)(ad2v + l * 4);
            ss = wv.x * av.x + wv.y * av.y + wv.z * av.z + wv.w * av.w;
            sd = wv.x * bv.x + wv.y * bv.y + wv.z * bv.z + wv.w * bv.w;
        }
        #pragma unroll
        for (int off = 1; off < 32; off <<= 1) { ss += __shfl_xor(ss, off); sd += __shfl_xor(sd, off); }
        if (l == 0) {
            if (task < 256) {
                int d = task & 127, h = task >> 7;
                U1[h * 128 + d] = ss;
                U1[256 + h * 128 + d] = sd;
            } else {
                int k = task - 256;
                U2[k] = ss;
                U2[256 + k] = sd;
            }
        }
    } else {
        int i = (blockIdx.x - 64) * 256 + threadIdx.x;
        if (i < 32768) {                                   // W1t [256][128], W1 [128][256]
            int n = i >> 7, k = i & 127;
            W1t[i] = f2bf(W1[k * 256 + n]);
        } else if (i < 65536) {                            // W2t [128][256], W2 [256][128]
            int j = i - 32768;
            int n = j >> 8, k = j & 255;
            W2t[j] = f2bf(W2[k * 128 + n]);
        } else if (i < 114688) {                           // Wlt [128][384], Wl [384][96]
            int j = i - 65536;
            int n = j / 384, k = j % 384;
            Wlt[j] = (n < 96) ? f2bf(Wl[(size_t)k * 96 + n]) : (unsigned short)0;
        }
    }
}

// ================= cast x -> bf16 fused with conv1 attention dots =================
__global__ __launch_bounds__(256) void cast_x_att(
    const float* __restrict__ x, const float* __restrict__ U1,
    unsigned short* __restrict__ xb, float* __restrict__ as1, float* __restrict__ ad1)
{
    __shared__ float Us[512];
    int tid = threadIdx.x;
    Us[tid] = U1[tid];
    Us[tid + 256] = U1[tid + 256];
    __syncthreads();
    int g = tid >> 5, l = tid & 31;
    int n = blockIdx.x * 8 + g;
    if (n >= NNODES) return;
    const float4 v = *(const float4*)(x + (size_t)n * 128 + l * 4);
    ushort4v o;
    o.x = f2bf(v.x); o.y = f2bf(v.y); o.z = f2bf(v.z); o.w = f2bf(v.w);
    *(ushort4v*)(xb + (size_t)n * 128 + l * 4) = o;
    const float4 us0 = *(const float4*)(Us + l * 4);
    const float4 us1 = *(const float4*)(Us + 128 + l * 4);
    const float4 ud0 = *(const float4*)(Us + 256 + l * 4);
    const float4 ud1 = *(const float4*)(Us + 384 + l * 4);
    float s0 = v.x * us0.x + v.y * us0.y + v.z * us0.z + v.w * us0.w;
    float s1 = v.x * us1.x + v.y * us1.y + v.z * us1.z + v.w * us1.w;
    float d0 = v.x * ud0.x + v.y * ud0.y + v.z * ud0.z + v.w * ud0.w;
    float d1 = v.x * ud1.x + v.y * ud1.y + v.z * ud1.z + v.w * ud1.w;
    #pragma unroll
    for (int off = 1; off < 32; off <<= 1) {
        s0 += __shfl_xor(s0, off); s1 += __shfl_xor(s1, off);
        d0 += __shfl_xor(d0, off); d1 += __shfl_xor(d1, off);
    }
    if (l == 0) {
        as1[n * 2] = s0; as1[n * 2 + 1] = s1;
        ad1[n * 2] = d0; ad1[n * 2 + 1] = d1;
    }
}

// ================= fused BN-finalize + weight-fold kernels =================
__global__ void bnfold_a(const float* __restrict__ csum, const float* __restrict__ csq,
                         const float* __restrict__ gamma, const float* __restrict__ beta,
                         const float* __restrict__ Wa, const float* __restrict__ ba,
                         unsigned short* __restrict__ Wat2, float* __restrict__ ba_f) {
    __shared__ float scl[96], shf[96];
    int tid = threadIdx.x;
    if (tid < 96) {
        float mu  = csum[tid] / (float)NNODES;
        float var = csq[tid] / (float)NNODES - mu * mu;
        if (var < 0.f) var = 0.f;
        float sc = gamma[tid] * rsqrtf(var + 1e-5f);
        scl[tid] = sc; shf[tid] = beta[tid] - mu * sc;
    }
    __syncthreads();
    for (int idx = tid; idx < 128 * 96; idx += 256) {
        int n = idx / 96, k = idx % 96;
        Wat2[idx] = (n < 96) ? f2bf(scl[k] * Wa[k * 96 + n]) : (unsigned short)0;
    }
    if (tid < 96) {
        float s = ba[tid];
        for (int k = 0; k < 96; ++k) s += shf[k] * Wa[k * 96 + tid];
        ba_f[tid] = s;
    }
}

__global__ void bnfold_b(const float* __restrict__ csum, const float* __restrict__ csq,
                         const float* __restrict__ gamma, const float* __restrict__ beta,
                         const float* __restrict__ Wb, const float* __restrict__ bb,
                         unsigned short* __restrict__ Wbt, float* __restrict__ bb_f) {
    __shared__ float scl[96], shf[96];
    int tid = threadIdx.x;
    if (tid < 96) {
        float mu  = csum[tid] / (float)NNODES;
        float var = csq[tid] / (float)NNODES - mu * mu;
        if (var < 0.f) var = 0.f;
        float sc = gamma[tid] * rsqrtf(var + 1e-5f);
        scl[tid] = sc; shf[tid] = beta[tid] - mu * sc;
    }
    __syncthreads();
    for (int idx = tid; idx < 64 * 96; idx += 256) {
        int n = idx / 96, k = idx % 96;
        Wbt[idx] = (n < 2) ? f2bf(scl[k] * Wb[k * 2 + n]) : (unsigned short)0;
    }
    if (tid < 2) {
        float s = bb[tid];
        for (int k = 0; k < 96; ++k) s += shf[k] * Wb[k * 2 + tid];
        bb_f[tid] = s;
    }
}

__global__ void bn_fin_apply(const float* __restrict__ csum, const float* __restrict__ csq,
                             const float* __restrict__ gamma, const float* __restrict__ beta,
                             float* __restrict__ y, int total) {
    int i = blockIdx.x * blockDim.x + threadIdx.x;
    if (i >= total) return;
    int j = i & 1;
    float mu  = csum[j] / (float)NNODES;
    float var = csq[j] / (float)NNODES - mu * mu;
    if (var < 0.f) var = 0.f;
    float sc = gamma[j] * rsqrtf(var + 1e-5f);
    float sh = beta[j] - mu * sc;
    y[i] = y[i] * sc + sh;
}

__device__ __forceinline__ void edge_src_dst(const int* ei, int e, int& src, int& dst) {
    if (e < NEDGES) { src = ei[e]; dst = ei[NEDGES + e]; }
    else { src = e - NEDGES; dst = src; }
}

// ================= CSR build =================
__global__ __launch_bounds__(256) void csr_count(const int* __restrict__ ei, int* __restrict__ cnt) {
    int e = blockIdx.x * blockDim.x + threadIdx.x;
    if (e >= ETOT) return;
    int src, dst; edge_src_dst(ei, e, src, dst); (void)src;
    atomicAdd(&cnt[dst], 1);
}

#define SCAN_CH 1024
#define SCAN_NB ((NNODES + SCAN_CH - 1) / SCAN_CH)   // 49

__global__ __launch_bounds__(256) void scan1(const int* __restrict__ cnt, int* __restrict__ part) {
    int t = threadIdx.x;
    int base = blockIdx.x * SCAN_CH + t * 4;
    int4 v = {0, 0, 0, 0};
    if (base + 3 < NNODES) v = *(const int4*)(cnt + base);
    else {
        if (base + 0 < NNODES) v.x = cnt[base + 0];
        if (base + 1 < NNODES) v.y = cnt[base + 1];
        if (base + 2 < NNODES) v.z = cnt[base + 2];
        if (base + 3 < NNODES) v.w = cnt[base + 3];
    }
    int s = v.x + v.y + v.z + v.w;
    __shared__ int sm[256];
    sm[t] = s;
    __syncthreads();
    for (int off = 128; off > 0; off >>= 1) {
        if (t < off) sm[t] += sm[t + off];
        __syncthreads();
    }
    if (t == 0) part[blockIdx.x] = sm[0];
}

// scan2 folded in: wave 0 of every block redundantly exclusive-scans the 49 partials.
__global__ __launch_bounds__(256) void scan23(const int* __restrict__ cnt, const int* __restrict__ part,
                                              int* __restrict__ rowstart, int* __restrict__ cursor) {
    __shared__ int sbase;
    int t = threadIdx.x;
    if (t < 64) {
        int v = (t < SCAN_NB) ? part[t] : 0;
        #pragma unroll
        for (int off = 1; off < 64; off <<= 1) {
            int u = __shfl_up(v, off);
            if (t >= off) v += u;
        }
        int ex = __shfl_up(v, 1);
        if (t == 0) ex = 0;
        if (t == (int)blockIdx.x) sbase = ex;
        if (blockIdx.x == 0 && t == 0) rowstart[NNODES] = ETOT;
    }
    int base = blockIdx.x * SCAN_CH + t * 4;
    int4 v = {0, 0, 0, 0};
    if (base + 3 < NNODES) v = *(const int4*)(cnt + base);
    else {
        if (base + 0 < NNODES) v.x = cnt[base + 0];
        if (base + 1 < NNODES) v.y = cnt[base + 1];
        if (base + 2 < NNODES) v.z = cnt[base + 2];
        if (base + 3 < NNODES) v.w = cnt[base + 3];
    }
    int s = v.x + v.y + v.z + v.w;
    __shared__ int sm[2][256];
    sm[0][t] = s;
    __syncthreads();
    int cur = 0;
    #pragma unroll
    for (int off = 1; off < 256; off <<= 1) {
        int nxt = cur ^ 1;
        int val = sm[cur][t];
        if (t >= off) val += sm[cur][t - off];
        sm[nxt][t] = val;
        __syncthreads();
        cur = nxt;
    }
    int p = sm[cur][t] - s + sbase;
    if (base + 0 < NNODES) { rowstart[base + 0] = p; cursor[base + 0] = p; } p += v.x;
    if (base + 1 < NNODES) { rowstart[base + 1] = p; cursor[base + 1] = p; } p += v.y;
    if (base + 2 < NNODES) { rowstart[base + 2] = p; cursor[base + 2] = p; } p += v.z;
    if (base + 3 < NNODES) { rowstart[base + 3] = p; cursor[base + 3] = p; }
}

__global__ __launch_bounds__(256) void csr_fill(const int* __restrict__ ei,
                                                int* __restrict__ cursor,
                                                int* __restrict__ esrc) {
    int e = blockIdx.x * blockDim.x + threadIdx.x;
    if (e >= ETOT) return;
    int src, dst; edge_src_dst(ei, e, src, dst);
    int pos = atomicAdd(&cursor[dst], 1);
    esrc[pos] = src;
}

// ======== conv1+conv2 FUSED: gather x + W1 MFMA + bias + att2 + W2 MFMA ========
// 16 nodes/block (grid 3125, exact). Phase 1: per-16-lane-group register softmax
// (deg<=32 2-slot) aggregates x into regs -> LDS A-tile [16][264]. Phase 2: 4 waves
// x 16 MFMA: C1[16][256] = A @ W1 (block-diag heads). After a barrier the bf16
// C1 (+bias) overwrites the A-tile in LDS; conv2 att dots done here (U2, atomics).
// xcat[:, :256] stored with coalesced 16B chunks from LDS. Phase 3: 16 MFMA/wave:
// hb2[16][128] = C1 @ W2 (K=256) -> the standalone conv2 GEMM launch + its xcat
// re-read are gone. NOTE hb2 must NOT alias xb (other blocks still gather xb).
__global__ __launch_bounds__(256, 8) void gat_conv12_fused(
    const int* __restrict__ rowstart, const int* __restrict__ esrc,
    const unsigned short* __restrict__ xb, const float* __restrict__ a_src,
    const float* __restrict__ a_dst, const unsigned short* __restrict__ W1t,
    const unsigned short* __restrict__ W2t,
    const float* __restrict__ bias1, const float* __restrict__ U2,
    unsigned short* __restrict__ xcat, unsigned short* __restrict__ hb2,
    float* __restrict__ as2, float* __restrict__ ad2)
{
    __shared__ __attribute__((aligned(16))) unsigned short Alds[16 * 264];
    __shared__ float U2s[512];
    __shared__ float Bs[256];

    int tid = threadIdx.x;
    int t = tid & 15;
    int g = tid >> 4;                 // node group 0..15
    int nb = blockIdx.x * 16;
    int n = nb + g;                   // always < NNODES (50000 = 3125*16)

    U2s[tid] = U2[tid];
    U2s[tid + 256] = U2[tid + 256];
    Bs[tid] = bias1[tid];

    // ---- phase 1: gather ----
    int beg = rowstart[n], deg = rowstart[n + 1] - beg;
    const float2 adv = *(const float2*)(a_dst + (size_t)n * 2);
    float acc0[8] = {}, acc1[8] = {};

    if (deg <= 32) {
        int sa = 0, sb = 0;
        float la0 = -1e30f, la1 = -1e30f;
        float lb0 = -1e30f, lb1 = -1e30f;
        if (t < deg) {
            sa = esrc[beg + t];
            const float2 asv = *(const float2*)(a_src + (size_t)sa * 2);
            la0 = asv.x + adv.x; la0 = la0 >= 0.f ? la0 : 0.2f * la0;
            lb0 = asv.y + adv.y; lb0 = lb0 >= 0.f ? lb0 : 0.2f * lb0;
        }
        if (t + 16 < deg) {
            sb = esrc[beg + 16 + t];
            const float2 asv = *(const float2*)(a_src + (size_t)sb * 2);
            la1 = asv.x + adv.x; la1 = la1 >= 0.f ? la1 : 0.2f * la1;
            lb1 = asv.y + adv.y; lb1 = lb1 >= 0.f ? lb1 : 0.2f * lb1;
        }
        float m0 = fmaxf(la0, la1), m1 = fmaxf(lb0, lb1);
        #pragma unroll
        for (int off = 1; off < 16; off <<= 1) {
            m0 = fmaxf(m0, __shfl_xor(m0, off, 16));
            m1 = fmaxf(m1, __shfl_xor(m1, off, 16));
        }
        float ea0 = (t < deg)      ? __expf(la0 - m0) : 0.f;
        float ea1 = (t + 16 < deg) ? __expf(la1 - m0) : 0.f;
        float eb0 = (t < deg)      ? __expf(lb0 - m1) : 0.f;
        float eb1 = (t + 16 < deg) ? __expf(lb1 - m1) : 0.f;
        float s0 = ea0 + ea1, s1 = eb0 + eb1;
        #pragma unroll
        for (int off = 1; off < 16; off <<= 1) {
            s0 += __shfl_xor(s0, off, 16);
            s1 += __shfl_xor(s1, off, 16);
        }
        float i0 = 1.f / (s0 + 1e-16f), i1 = 1.f / (s1 + 1e-16f);
        float wa0 = ea0 * i0, wa1 = ea1 * i0;
        float wb0 = eb0 * i1, wb1 = eb1 * i1;

        int e = 0;
        for (; e + 3 < deg; e += 4) {
            int sx[4]; float w0x[4], w1x[4];
            #pragma unroll
            for (int u = 0; u < 4; ++u) {
                int ee = e + u;
                int hi = ee & 16, ln = ee & 15;
                sx[u]  = __shfl(hi ? sb  : sa,  ln, 16);
                w0x[u] = __shfl(hi ? wa1 : wa0, ln, 16);
                w1x[u] = __shfl(hi ? wb1 : wb0, ln, 16);
            }
            ushort8v hv[4];
            #pragma unroll
            for (int u = 0; u < 4; ++u)
                hv[u] = *(const ushort8v*)(xb + (size_t)sx[u] * 128 + t * 8);
            #pragma unroll
            for (int u = 0; u < 4; ++u) {
                #pragma unroll
                for (int j = 0; j < 8; ++j) {
                    float f = bf2f(hv[u][j]);
                    acc0[j] += w0x[u] * f;
                    acc1[j] += w1x[u] * f;
                }
            }
        }
        for (; e < deg; ++e) {
            int hi = e & 16, ln = e & 15;
            int   sX  = __shfl(hi ? sb  : sa,  ln, 16);
            float wX0 = __shfl(hi ? wa1 : wa0, ln, 16);
            float wX1 = __shfl(hi ? wb1 : wb0, ln, 16);
            const ushort8v hv = *(const ushort8v*)(xb + (size_t)sX * 128 + t * 8);
            #pragma unroll
            for (int j = 0; j < 8; ++j) {
                float f = bf2f(hv[j]);
                acc0[j] += wX0 * f; acc1[j] += wX1 * f;
            }
        }
    } else {
        // rare fallback (P[Pois(10)>31] ~ 2e-9)
        float m0 = -1e30f, m1 = -1e30f;
        for (int idx = t; idx < deg; idx += 16) {
            int s = esrc[beg + idx];
            const float2 asv = *(const float2*)(a_src + (size_t)s * 2);
            float l0 = asv.x + adv.x; l0 = l0 >= 0.f ? l0 : 0.2f * l0;
            float l1 = asv.y + adv.y; l1 = l1 >= 0.f ? l1 : 0.2f * l1;
            m0 = fmaxf(m0, l0); m1 = fmaxf(m1, l1);
        }
        #pragma unroll
        for (int off = 1; off < 16; off <<= 1) {
            m0 = fmaxf(m0, __shfl_xor(m0, off, 16));
            m1 = fmaxf(m1, __shfl_xor(m1, off, 16));
        }
        float s0 = 0.f, s1 = 0.f;
        for (int idx = t; idx < deg; idx += 16) {
            int s = esrc[beg + idx];
            const float2 asv = *(const float2*)(a_src + (size_t)s * 2);
            float l0 = asv.x + adv.x; l0 = l0 >= 0.f ? l0 : 0.2f * l0;
            float l1 = asv.y + adv.y; l1 = l1 >= 0.f ? l1 : 0.2f * l1;
            s0 += __expf(l0 - m0); s1 += __expf(l1 - m1);
        }
        #pragma unroll
        for (int off = 1; off < 16; off <<= 1) {
            s0 += __shfl_xor(s0, off, 16);
            s1 += __shfl_xor(s1, off, 16);
        }
        float inv0 = 1.f / (s0 + 1e-16f), inv1 = 1.f / (s1 + 1e-16f);
        for (int e = 0; e < deg; ++e) {
            int s = esrc[beg + e];
            const float2 asv = *(const float2*)(a_src + (size_t)s * 2);
            float l0 = asv.x + adv.x; l0 = l0 >= 0.f ? l0 : 0.2f * l0;
            float l1 = asv.y + adv.y; l1 = l1 >= 0.f ? l1 : 0.2f * l1;
            float w0 = __expf(l0 - m0) * inv0, w1 = __expf(l1 - m1) * inv1;
            const ushort8v hv = *(const ushort8v*)(xb + (size_t)s * 128 + t * 8);
            #pragma unroll
            for (int j = 0; j < 8; ++j) {
                float f = bf2f(hv[j]);
                acc0[j] += w0 * f; acc1[j] += w1 * f;
            }
        }
    }

    // store A-tile (bf16): row g, head0 cols [t*8..), head1 cols [128+t*8..)
    {
        ushort8v o0, o1;
        #pragma unroll
        for (int j = 0; j < 8; ++j) { o0[j] = f2bf(acc0[j]); o1[j] = f2bf(acc1[j]); }
        *(ushort8v*)(Alds + g * 264 + t * 8) = o0;
        *(ushort8v*)(Alds + g * 264 + 128 + t * 8) = o1;
    }
    __syncthreads();

    // ---- phase 2: C1[16][256] = A @ W1 (block-diag heads) ----
    int wave = tid >> 6, lane = tid & 63;
    int m = lane & 15, q = lane >> 4;
    int ncol0 = wave * 64;                 // 0,64 = head0; 128,192 = head1
    int kbase = (wave >= 2) ? 128 : 0;     // A K-columns for this head

    floatx4 cacc[4] = {};
    #pragma unroll
    for (int ks = 0; ks < 4; ++ks) {
        short8 a = *(const short8*)(Alds + m * 264 + kbase + ks * 32 + q * 8);
        #pragma unroll
        for (int ct = 0; ct < 4; ++ct) {
            short8 b = *(const short8*)(W1t + (size_t)(ncol0 + ct * 16 + m) * 128 + ks * 32 + q * 8);
            cacc[ct] = __builtin_amdgcn_mfma_f32_16x16x32_bf16(a, b, cacc[ct], 0, 0, 0);
        }
    }
    __syncthreads();   // all A-tile reads done; safe to overwrite with C1

    // epilogue: C1+bias -> LDS (bf16), conv2 att dots
    #pragma unroll
    for (int r = 0; r < 4; ++r) {
        int row = q * 4 + r;               // 0..15
        int gn = nb + row;
        float ds = 0.f, dd = 0.f;
        #pragma unroll
        for (int ct = 0; ct < 4; ++ct) {
            int col = ncol0 + ct * 16 + m;
            float vb = cacc[ct][r] + Bs[col];
            ds += vb * U2s[col];
            dd += vb * U2s[256 + col];
            Alds[row * 264 + col] = f2bf(vb);
        }
        #pragma unroll
        for (int off = 1; off < 16; off <<= 1) {
            ds += __shfl_xor(ds, off);
            dd += __shfl_xor(dd, off);
        }
        if (m == 0) {
            atomicAdd(&as2[gn], ds);
            atomicAdd(&ad2[gn], dd);
        }
    }
    __syncthreads();   // C1 tile complete in LDS

    // coalesced xcat[:, :256] store: 16 rows x 32 16B-chunks = 512 chunks
    #pragma unroll
    for (int c = tid; c < 512; c += 256) {
        int row = c >> 5, ch = c & 31;
        ushort8v v = *(const ushort8v*)(Alds + row * 264 + ch * 8);
        *(ushort8v*)(xcat + (size_t)(nb + row) * 384 + ch * 8) = v;
    }

    // ---- phase 3: hb2[16][128] = C1 @ W2 (K=256) ----
    floatx4 c2[2] = {};
    #pragma unroll
    for (int ks = 0; ks < 8; ++ks) {
        short8 a = *(const short8*)(Alds + m * 264 + ks * 32 + q * 8);
        #pragma unroll
        for (int ct = 0; ct < 2; ++ct) {
            int col = wave * 32 + ct * 16 + m;
            short8 b = *(const short8*)(W2t + (size_t)col * 256 + ks * 32 + q * 8);
            c2[ct] = __builtin_amdgcn_mfma_f32_16x16x32_bf16(a, b, c2[ct], 0, 0, 0);
        }
    }
    #pragma unroll
    for (int r = 0; r < 4; ++r) {
        int row = q * 4 + r;
        int gn = nb + row;
        #pragma unroll
        for (int ct = 0; ct < 2; ++ct) {
            int col = wave * 32 + ct * 16 + m;
            hb2[(size_t)gn * 128 + col] = f2bf(c2[ct][r]);
        }
    }
}

// conv2 (H=1, 128 feats): 2-slot register softmax (deg<=32), unroll-4 gathers.
__global__ __launch_bounds__(256) void gat_gather_h1(
    const int* __restrict__ rowstart, const int* __restrict__ esrc,
    const unsigned short* __restrict__ hb, const float* __restrict__ a_src,
    const float* __restrict__ a_dst, const float* __restrict__ bias,
    unsigned short* __restrict__ xcat)
{
    int tid = threadIdx.x;
    int t = tid & 15;
    int g0 = (blockIdx.x * blockDim.x + tid) >> 4;
    int gstride = (gridDim.x * blockDim.x) >> 4;

    for (int n = g0; n < NNODES; n += gstride) {
        int beg = rowstart[n], deg = rowstart[n + 1] - beg;
        float ad0 = a_dst[n];
        float acc[8] = {};

        if (deg <= 32) {
            int sa = 0, sb = 0;
            float l0 = -1e30f, l1 = -1e30f;
            if (t < deg) {
                sa = esrc[beg + t];
                l0 = a_src[sa] + ad0; l0 = l0 >= 0.f ? l0 : 0.2f * l0;
            }
            if (t + 16 < deg) {
                sb = esrc[beg + 16 + t];
                l1 = a_src[sb] + ad0; l1 = l1 >= 0.f ? l1 : 0.2f * l1;
            }
            float m0 = fmaxf(l0, l1);
            #pragma unroll
            for (int off = 1; off < 16; off <<= 1)
                m0 = fmaxf(m0, __shfl_xor(m0, off, 16));
            float e0 = (t < deg)      ? __expf(l0 - m0) : 0.f;
            float e1 = (t + 16 < deg) ? __expf(l1 - m0) : 0.f;
            float s0 = e0 + e1;
            #pragma unroll
            for (int off = 1; off < 16; off <<= 1)
                s0 += __shfl_xor(s0, off, 16);
            float i0 = 1.f / (s0 + 1e-16f);
            float w0 = e0 * i0, w1 = e1 * i0;

            int e = 0;
            for (; e + 3 < deg; e += 4) {
                int sx[4]; float wx[4];
                #pragma unroll
                for (int u = 0; u < 4; ++u) {
                    int ee = e + u;
                    int hi = ee & 16, ln = ee & 15;
                    sx[u] = __shfl(hi ? sb : sa, ln, 16);
                    wx[u] = __shfl(hi ? w1 : w0, ln, 16);
                }
                ushort8v hv[4];
                #pragma unroll
                for (int u = 0; u < 4; ++u)
                    hv[u] = *(const ushort8v*)(hb + (size_t)sx[u] * 128 + t * 8);
                #pragma unroll
                for (int u = 0; u < 4; ++u) {
                    #pragma unroll
                    for (int j = 0; j < 8; ++j)
                        acc[j] += wx[u] * bf2f(hv[u][j]);
                }
            }
            for (; e < deg; ++e) {
                int hi = e & 16, ln = e & 15;
                int   sX = __shfl(hi ? sb : sa, ln, 16);
                float wX = __shfl(hi ? w1 : w0, ln, 16);
                const ushort8v hv = *(const ushort8v*)(hb + (size_t)sX * 128 + t * 8);
                #pragma unroll
                for (int j = 0; j < 8; ++j) acc[j] += wX * bf2f(hv[j]);
            }
        } else {
            float m0 = -1e30f;
            for (int idx = t; idx < deg; idx += 16) {
                int s = esrc[beg + idx];
                float l = a_src[s] + ad0; l = l >= 0.f ? l : 0.2f * l;
                m0 = fmaxf(m0, l);
            }
            #pragma unroll
            for (int off = 1; off < 16; off <<= 1)
                m0 = fmaxf(m0, __shfl_xor(m0, off, 16));
            float s0 = 0.f;
            for (int idx = t; idx < deg; idx += 16) {
                int s = esrc[beg + idx];
                float l = a_src[s] + ad0; l = l >= 0.f ? l : 0.2f * l;
                s0 += __expf(l - m0);
            }
            #pragma unroll
            for (int off = 1; off < 16; off <<= 1)
                s0 += __shfl_xor(s0, off, 16);
            float inv0 = 1.f / (s0 + 1e-16f);
            for (int e = 0; e < deg; ++e) {
                int s = esrc[beg + e];
                float l = a_src[s] + ad0; l = l >= 0.f ? l : 0.2f * l;
                float w = __expf(l - m0) * inv0;
                const ushort8v hv = *(const ushort8v*)(hb + (size_t)s * 128 + t * 8);
                #pragma unroll
                for (int j = 0; j < 8; ++j) acc[j] += w * bf2f(hv[j]);
            }
        }

        const float4 b0 = *(const float4*)(bias + t * 8);
        const float4 b1 = *(const float4*)(bias + t * 8 + 4);
        ushort8v o;
        o[0] = f2bf(acc[0] + b0.x); o[1] = f2bf(acc[1] + b0.y);
        o[2] = f2bf(acc[2] + b0.z); o[3] = f2bf(acc[3] + b0.w);
        o[4] = f2bf(acc[4] + b1.x); o[5] = f2bf(acc[5] + b1.y);
        o[6] = f2bf(acc[6] + b1.z); o[7] = f2bf(acc[7] + b1.w);
        *(ushort8v*)(xcat + (size_t)n * 384 + 256 + t * 8) = o;
    }
}

extern "C" void kernel_launch(void* const* d_in, const int* in_sizes, int n_in,
                              void* d_out, int out_size, void* d_ws, size_t ws_size,
                              hipStream_t stream) {
    const float* x        = (const float*)d_in[0];
    const int*   ei       = (const int*)d_in[1];
    const float* W1       = (const float*)d_in[2];
    const float* att_src1 = (const float*)d_in[3];
    const float* att_dst1 = (const float*)d_in[4];
    const float* bias1    = (const float*)d_in[5];
    const float* W2       = (const float*)d_in[6];
    const float* att_src2 = (const float*)d_in[7];
    const float* att_dst2 = (const float*)d_in[8];
    const float* bias2    = (const float*)d_in[9];
    const float* Wl       = (const float*)d_in[10];
    const float* bl       = (const float*)d_in[11];
    const float* gl       = (const float*)d_in[12];
    const float* betal    = (const float*)d_in[13];
    const float* Wa       = (const float*)d_in[14];
    const float* ba       = (const float*)d_in[15];
    const float* ga       = (const float*)d_in[16];
    const float* betaa    = (const float*)d_in[17];
    const float* Wb       = (const float*)d_in[18];
    const float* bb       = (const float*)d_in[19];
    const float* gb       = (const float*)d_in[20];
    const float* betab    = (const float*)d_in[21];
    float* out = (float*)d_out;
    char* ws = (char*)d_ws;

    const int N = NNODES;

    // ---------- workspace layout (bytes) ----------
    const size_t offY2b  = 0;            //  9.6 MB: y2b bf16 [50000][96]
    const size_t offXcat = 19200000;     // 38.4 MB: xcat bf16 [50000][384]
    const size_t offXb   = 57600000;     // 12.8 MB: xb bf16 [50000][128]
    const size_t offY1b  = 70400000;     //  9.6 MB: y1b bf16 [50000][96]
    const size_t offHb2  = 80000000;     // 12.8 MB: hb2 bf16 [50000][128] (must NOT alias xb)
    const size_t offW1t  = 105600000;    // 64 KB
    const size_t offW2t  = 105665536;    // 64 KB
    const size_t offWlt  = 105731072;    // 96 KB
    const size_t offWat2 = 105829376;    // folded Wa bf16 [128][96]
    const size_t offWbt  = 105853952;    // folded Wb bf16 [64][96]
    const size_t offBaf  = 105866240;    // folded ba [96] f32
    const size_t offBbf  = 105866640;    // folded bb [2] f32
    const size_t offU1   = 105867264;    // U1 [512] f32 (W1-folded att vecs)
    const size_t offU2   = 105869312;    // U2 [512] f32 (W2-folded att vecs)
    const size_t offRow  = 106000000;    // cnt -> rowstart [N+1] ints
    const size_t offCur  = 106200128;    // cursor [N] ints
    const size_t offEsrc = 106400832;    // esrc [ETOT] ints
    const size_t offPart = 108700000;    // scan partials [64] ints
    const size_t offAs1  = 108800000;    // a_src1 [N*2] f32
    const size_t offAd1  = 109200000;
    const size_t offAs2  = 109600000;
    const size_t offAd2  = 109800000;
    const size_t offSt   = 110000000;    // stats

    unsigned short* y2b   = (unsigned short*)(ws + offY2b);
    unsigned short* xcat  = (unsigned short*)(ws + offXcat);
    unsigned short* xb    = (unsigned short*)(ws + offXb);
    unsigned short* y1b   = (unsigned short*)(ws + offY1b);
    unsigned short* hb2   = (unsigned short*)(ws + offHb2);
    unsigned short* W1t   = (unsigned short*)(ws + offW1t);
    unsigned short* W2t   = (unsigned short*)(ws + offW2t);
    unsigned short* Wlt   = (unsigned short*)(ws + offWlt);
    unsigned short* Wat2  = (unsigned short*)(ws + offWat2);
    unsigned short* Wbt   = (unsigned short*)(ws + offWbt);
    float* ba_f = (float*)(ws + offBaf);
    float* bb_f = (float*)(ws + offBbf);
    float* U1   = (float*)(ws + offU1);
    float* U2   = (float*)(ws + offU2);
    int* rowst  = (int*)(ws + offRow);
    int* cursor = (int*)(ws + offCur);
    int* esrc   = (int*)(ws + offEsrc);
    int* part   = (int*)(ws + offPart);
    float* as1  = (float*)(ws + offAs1);
    float* ad1  = (float*)(ws + offAd1);
    float* as2  = (float*)(ws + offAs2);
    float* ad2  = (float*)(ws + offAd2);

    float* csum_l = (float*)(ws + offSt + 0);
    float* csq_l  = (float*)(ws + offSt + 512);
    float* csum_a = (float*)(ws + offSt + 2048);
    float* csq_a  = (float*)(ws + offSt + 2560);
    float* csum_b = (float*)(ws + offSt + 4096);
    float* csq_b  = (float*)(ws + offSt + 4608);

    hipMemsetAsync(ws + offRow, 0, (NNODES + 1) * sizeof(int), stream);
    hipMemsetAsync(ws + offAs1, 0, (offSt + 6144) - offAs1, stream);

    dim3 blk(256);
    int edgeBlocks = (ETOT + 255) / 256;
    int gatherBlocks = 2048;             // 8192 waves, grid-stride (conv2 gather)
    dim3 gemmRows((N + GBM - 1) / GBM);

    // ---- fold att vectors + cast weights (merged); cast x fused with att1 dots ----
    fold_cast<<<512, blk, 0, stream>>>(W1, att_src1, att_dst1, W2, att_src2, att_dst2,
                                       Wl, U1, U2, W1t, W2t, Wlt);
    cast_x_att<<<(N + 7) / 8, blk, 0, stream>>>(x, U1, xb, as1, ad1);

    // ---- CSR build (scan2 folded into scan23) ----
    csr_count<<<edgeBlocks, blk, 0, stream>>>(ei, rowst);
    scan1<<<SCAN_NB, blk, 0, stream>>>(rowst, part);
    scan23<<<SCAN_NB, blk, 0, stream>>>(rowst, part, rowst, cursor);
    csr_fill<<<edgeBlocks, blk, 0, stream>>>(ei, cursor, esrc);

    // ---- conv1+conv2 fused: gather + W1 MFMA + bias + att2 dots + W2 MFMA ----
    gat_conv12_fused<<<NNODES / 16, blk, 0, stream>>>(
        rowst, esrc, xb, as1, ad1, W1t, W2t, bias1, U2, xcat, hb2, as2, ad2);

    // ---- conv2 aggregation ----
    gat_gather_h1<<<gatherBlocks, blk, 0, stream>>>(rowst, esrc, hb2, as2, ad2, bias2, xcat);

    // ---- lin1: y1b = bf16(relu(xcat @ Wl + bl)), stats; fold BN into Wa ----
    gemm_mfma<<<dim3(2, gemmRows.x), blk, 0, stream>>>(
        xcat, 384, Wlt, nullptr, y1b, 96, bl, csum_l, csq_l,
        N, 96, 384, 1);
    bnfold_a<<<1, 256, 0, stream>>>(csum_l, csq_l, gl, betal, Wa, ba, Wat2, ba_f);

    // ---- mlp1 layer 1: y2b = bf16(relu(y1b @ Wa' + ba')), stats; fold BN into Wb ----
    gemm_mfma<<<dim3(2, gemmRows.x), blk, 0, stream>>>(
        y1b, 96, Wat2, nullptr, y2b, 96, ba_f, csum_a, csq_a,
        N, 96, 96, 1);
    bnfold_b<<<1, 256, 0, stream>>>(csum_a, csq_a, ga, betaa, Wb, bb, Wbt, bb_f);

    // ---- mlp1 layer 2: out = relu(y2b @ Wb' + bb'), stats (MFMA, N=2) ----
    gemm_mfma<<<dim3(1, gemmRows.x), blk, 0, stream>>>(
        y2b, 96, Wbt, out, nullptr, 2, bb_f, csum_b, csq_b,
        N, 2, 96, 1);

    // ---- final BN (fused finalize+apply) ----
    bn_fin_apply<<<(N * 2 + 255) / 256, blk, 0, stream>>>(csum_b, csq_b, gb, betab, out, N * 2);
}

// Round 7
// 361.500 us; speedup vs baseline: 1.0068x; 1.0068x over previous
//
#include <hip/hip_runtime.h>
#include <hip/hip_bf16.h>
#include <cstdint>
#include <cstddef>

#define NNODES 50000
#define NEDGES 500000
#define ETOT   (NEDGES + NNODES)

typedef __attribute__((ext_vector_type(8))) short short8;
typedef __attribute__((ext_vector_type(8))) unsigned short ushort8v;
typedef __attribute__((ext_vector_type(4))) float floatx4;
typedef __attribute__((ext_vector_type(4))) unsigned short ushort4v;

__device__ __forceinline__ unsigned short f2bf(float f) {
    union { __hip_bfloat16 h; unsigned short u; } cv;
    cv.h = __float2bfloat16(f);
    return cv.u;
}
__device__ __forceinline__ float bf2f(unsigned short u) {
    union { unsigned int i; float f; } cv;
    cv.i = ((unsigned int)u) << 16;
    return cv.f;
}

// ================= bf16 MFMA GEMM: C/Cb = op(A @ Bt^T + bias) =================
#define GBM 128
#define GBN 64
#define GBK 32

__global__ __launch_bounds__(256, 4) void gemm_mfma(
    const unsigned short* __restrict__ A, int lda,
    const unsigned short* __restrict__ Bt,
    float* __restrict__ C,
    unsigned short* __restrict__ Cb, int ldc,
    const float* __restrict__ bias,
    float* __restrict__ colsum, float* __restrict__ colsq,
    int M, int N, int K, int do_relu)
{
    __shared__ __attribute__((aligned(16))) unsigned short Alds[GBM * GBK];
    __shared__ __attribute__((aligned(16))) unsigned short Blds[GBN * GBK];
    __shared__ float scol[GBN], sqcol[GBN];

    int tid = threadIdx.x;
    int wave = tid >> 6, lane = tid & 63;
    int row0 = blockIdx.y * GBM;
    int col0 = blockIdx.x * GBN;
    int m = lane & 15, q = lane >> 4;

    floatx4 acc[2][4] = {};

    for (int k0 = 0; k0 < K; k0 += GBK) {
        #pragma unroll
        for (int i = 0; i < 2; ++i) {
            int c = tid + i * 256;
            int r = c >> 2, off = (c & 3) * 8;
            int gr = row0 + r;
            short8 v = {};
            if (gr < M) v = *(const short8*)(A + (size_t)gr * lda + k0 + off);
            *(short8*)(Alds + r * GBK + off) = v;
        }
        {
            int r = tid >> 2, off = (tid & 3) * 8;
            short8 v = *(const short8*)(Bt + (size_t)(col0 + r) * K + k0 + off);
            *(short8*)(Blds + r * GBK + off) = v;
        }
        __syncthreads();

        short8 a0 = *(const short8*)(Alds + (wave * 32 + m) * GBK + q * 8);
        short8 a1 = *(const short8*)(Alds + (wave * 32 + 16 + m) * GBK + q * 8);
        #pragma unroll
        for (int ct = 0; ct < 4; ++ct) {
            short8 b = *(const short8*)(Blds + (ct * 16 + m) * GBK + q * 8);
            acc[0][ct] = __builtin_amdgcn_mfma_f32_16x16x32_bf16(a0, b, acc[0][ct], 0, 0, 0);
            acc[1][ct] = __builtin_amdgcn_mfma_f32_16x16x32_bf16(a1, b, acc[1][ct], 0, 0, 0);
        }
        __syncthreads();
    }

    float ps[4] = {}, pq[4] = {};
    #pragma unroll
    for (int rt = 0; rt < 2; ++rt) {
        #pragma unroll
        for (int r = 0; r < 4; ++r) {
            int gr = row0 + wave * 32 + rt * 16 + q * 4 + r;
            #pragma unroll
            for (int ct = 0; ct < 4; ++ct) {
                int gc = col0 + ct * 16 + m;
                float v = acc[rt][ct][r];
                if (gc < N) {
                    float vb = v;
                    if (bias != nullptr) vb += bias[gc];
                    if (do_relu) vb = fmaxf(vb, 0.f);
                    if (gr < M) {
                        if (C  != nullptr) C[(size_t)gr * ldc + gc] = vb;
                        if (Cb != nullptr) Cb[(size_t)gr * ldc + gc] = f2bf(vb);
                        ps[ct] += vb; pq[ct] += vb * vb;
                    }
                }
            }
        }
    }
    if (colsum != nullptr) {
        if (tid < GBN) { scol[tid] = 0.f; sqcol[tid] = 0.f; }
        __syncthreads();
        #pragma unroll
        for (int ct = 0; ct < 4; ++ct) {
            atomicAdd(&scol[ct * 16 + m], ps[ct]);
            atomicAdd(&sqcol[ct * 16 + m], pq[ct]);
        }
        __syncthreads();
        if (tid < GBN) {
            int gc = col0 + tid;
            if (gc < N) {
                atomicAdd(&colsum[gc], scol[tid]);
                atomicAdd(&colsq[gc], sqcol[tid]);
            }
        }
    }
}

// ================= fold att vectors through W1/W2 + cast weights (merged) ======
__global__ __launch_bounds__(256) void fold_cast(
    const float* __restrict__ W1, const float* __restrict__ as1v, const float* __restrict__ ad1v,
    const float* __restrict__ W2, const float* __restrict__ as2v, const float* __restrict__ ad2v,
    const float* __restrict__ Wl,
    float* __restrict__ U1, float* __restrict__ U2,
    unsigned short* __restrict__ W1t, unsigned short* __restrict__ W2t,
    unsigned short* __restrict__ Wlt)
{
    if (blockIdx.x < 64) {
        int g = threadIdx.x >> 5, l = threadIdx.x & 31;
        int task = blockIdx.x * 8 + g;   // 0..511
        float ss = 0.f, sd = 0.f;
        if (task < 256) {
            int d = task & 127, h = task >> 7;
            const float4 wv = *(const float4*)(W1 + d * 256 + h * 128 + l * 4);
            const float4 av = *(const float4*)(as1v + h * 128 + l * 4);
            const float4 bv = *(const float4*)(ad1v + h * 128 + l * 4);
            ss = wv.x * av.x + wv.y * av.y + wv.z * av.z + wv.w * av.w;
            sd = wv.x * bv.x + wv.y * bv.y + wv.z * bv.z + wv.w * bv.w;
        } else {
            int k = task - 256;
            const float4 wv = *(const float4*)(W2 + (size_t)k * 128 + l * 4);
            const float4 av = *(const float4*)(as2v + l * 4);
            const float4 bv = *(const float4*)(ad2v + l * 4);
            ss = wv.x * av.x + wv.y * av.y + wv.z * av.z + wv.w * av.w;
            sd = wv.x * bv.x + wv.y * bv.y + wv.z * bv.z + wv.w * bv.w;
        }
        #pragma unroll
        for (int off = 1; off < 32; off <<= 1) { ss += __shfl_xor(ss, off); sd += __shfl_xor(sd, off); }
        if (l == 0) {
            if (task < 256) {
                int d = task & 127, h = task >> 7;
                U1[h * 128 + d] = ss;
                U1[256 + h * 128 + d] = sd;
            } else {
                int k = task - 256;
                U2[k] = ss;
                U2[256 + k] = sd;
            }
        }
    } else {
        int i = (blockIdx.x - 64) * 256 + threadIdx.x;
        if (i < 32768) {                                   // W1t [256][128], W1 [128][256]
            int n = i >> 7, k = i & 127;
            W1t[i] = f2bf(W1[k * 256 + n]);
        } else if (i < 65536) {                            // W2t [128][256], W2 [256][128]
            int j = i - 32768;
            int n = j >> 8, k = j & 255;
            W2t[j] = f2bf(W2[k * 128 + n]);
        } else if (i < 114688) {                           // Wlt [128][384], Wl [384][96]
            int j = i - 65536;
            int n = j / 384, k = j % 384;
            Wlt[j] = (n < 96) ? f2bf(Wl[(size_t)k * 96 + n]) : (unsigned short)0;
        }
    }
}

// ================= cast x -> bf16 fused with conv1 attention dots =================
__global__ __launch_bounds__(256) void cast_x_att(
    const float* __restrict__ x, const float* __restrict__ U1,
    unsigned short* __restrict__ xb, float* __restrict__ as1, float* __restrict__ ad1)
{
    __shared__ float Us[512];
    int tid = threadIdx.x;
    Us[tid] = U1[tid];
    Us[tid + 256] = U1[tid + 256];
    __syncthreads();
    int g = tid >> 5, l = tid & 31;
    int n = blockIdx.x * 8 + g;
    if (n >= NNODES) return;
    const float4 v = *(const float4*)(x + (size_t)n * 128 + l * 4);
    ushort4v o;
    o.x = f2bf(v.x); o.y = f2bf(v.y); o.z = f2bf(v.z); o.w = f2bf(v.w);
    *(ushort4v*)(xb + (size_t)n * 128 + l * 4) = o;
    const float4 us0 = *(const float4*)(Us + l * 4);
    const float4 us1 = *(const float4*)(Us + 128 + l * 4);
    const float4 ud0 = *(const float4*)(Us + 256 + l * 4);
    const float4 ud1 = *(const float4*)(Us + 384 + l * 4);
    float s0 = v.x * us0.x + v.y * us0.y + v.z * us0.z + v.w * us0.w;
    float s1 = v.x * us1.x + v.y * us1.y + v.z * us1.z + v.w * us1.w;
    float d0 = v.x * ud0.x + v.y * ud0.y + v.z * ud0.z + v.w * ud0.w;
    float d1 = v.x * ud1.x + v.y * ud1.y + v.z * ud1.z + v.w * ud1.w;
    #pragma unroll
    for (int off = 1; off < 32; off <<= 1) {
        s0 += __shfl_xor(s0, off); s1 += __shfl_xor(s1, off);
        d0 += __shfl_xor(d0, off); d1 += __shfl_xor(d1, off);
    }
    if (l == 0) {
        as1[n * 2] = s0; as1[n * 2 + 1] = s1;
        ad1[n * 2] = d0; ad1[n * 2 + 1] = d1;
    }
}

// ================= fused BN-finalize + weight-fold kernels =================
__global__ void bnfold_a(const float* __restrict__ csum, const float* __restrict__ csq,
                         const float* __restrict__ gamma, const float* __restrict__ beta,
                         const float* __restrict__ Wa, const float* __restrict__ ba,
                         unsigned short* __restrict__ Wat2, float* __restrict__ ba_f) {
    __shared__ float scl[96], shf[96];
    int tid = threadIdx.x;
    if (tid < 96) {
        float mu  = csum[tid] / (float)NNODES;
        float var = csq[tid] / (float)NNODES - mu * mu;
        if (var < 0.f) var = 0.f;
        float sc = gamma[tid] * rsqrtf(var + 1e-5f);
        scl[tid] = sc; shf[tid] = beta[tid] - mu * sc;
    }
    __syncthreads();
    for (int idx = tid; idx < 128 * 96; idx += 256) {
        int n = idx / 96, k = idx % 96;
        Wat2[idx] = (n < 96) ? f2bf(scl[k] * Wa[k * 96 + n]) : (unsigned short)0;
    }
    if (tid < 96) {
        float s = ba[tid];
        for (int k = 0; k < 96; ++k) s += shf[k] * Wa[k * 96 + tid];
        ba_f[tid] = s;
    }
}

__global__ void bnfold_b(const float* __restrict__ csum, const float* __restrict__ csq,
                         const float* __restrict__ gamma, const float* __restrict__ beta,
                         const float* __restrict__ Wb, const float* __restrict__ bb,
                         unsigned short* __restrict__ Wbt, float* __restrict__ bb_f) {
    __shared__ float scl[96], shf[96];
    int tid = threadIdx.x;
    if (tid < 96) {
        float mu  = csum[tid] / (float)NNODES;
        float var = csq[tid] / (float)NNODES - mu * mu;
        if (var < 0.f) var = 0.f;
        float sc = gamma[tid] * rsqrtf(var + 1e-5f);
        scl[tid] = sc; shf[tid] = beta[tid] - mu * sc;
    }
    __syncthreads();
    for (int idx = tid; idx < 64 * 96; idx += 256) {
        int n = idx / 96, k = idx % 96;
        Wbt[idx] = (n < 2) ? f2bf(scl[k] * Wb[k * 2 + n]) : (unsigned short)0;
    }
    if (tid < 2) {
        float s = bb[tid];
        for (int k = 0; k < 96; ++k) s += shf[k] * Wb[k * 2 + tid];
        bb_f[tid] = s;
    }
}

__global__ void bn_fin_apply(const float* __restrict__ csum, const float* __restrict__ csq,
                             const float* __restrict__ gamma, const float* __restrict__ beta,
                             float* __restrict__ y, int total) {
    int i = blockIdx.x * blockDim.x + threadIdx.x;
    if (i >= total) return;
    int j = i & 1;
    float mu  = csum[j] / (float)NNODES;
    float var = csq[j] / (float)NNODES - mu * mu;
    if (var < 0.f) var = 0.f;
    float sc = gamma[j] * rsqrtf(var + 1e-5f);
    float sh = beta[j] - mu * sc;
    y[i] = y[i] * sc + sh;
}

__device__ __forceinline__ void edge_src_dst(const int* ei, int e, int& src, int& dst) {
    if (e < NEDGES) { src = ei[e]; dst = ei[NEDGES + e]; }
    else { src = e - NEDGES; dst = src; }
}

// ================= CSR build =================
__global__ __launch_bounds__(256) void csr_count(const int* __restrict__ ei, int* __restrict__ cnt) {
    int e = blockIdx.x * blockDim.x + threadIdx.x;
    if (e >= ETOT) return;
    int src, dst; edge_src_dst(ei, e, src, dst); (void)src;
    atomicAdd(&cnt[dst], 1);
}

#define SCAN_CH 1024
#define SCAN_NB ((NNODES + SCAN_CH - 1) / SCAN_CH)   // 49

__global__ __launch_bounds__(256) void scan1(const int* __restrict__ cnt, int* __restrict__ part) {
    int t = threadIdx.x;
    int base = blockIdx.x * SCAN_CH + t * 4;
    int4 v = {0, 0, 0, 0};
    if (base + 3 < NNODES) v = *(const int4*)(cnt + base);
    else {
        if (base + 0 < NNODES) v.x = cnt[base + 0];
        if (base + 1 < NNODES) v.y = cnt[base + 1];
        if (base + 2 < NNODES) v.z = cnt[base + 2];
        if (base + 3 < NNODES) v.w = cnt[base + 3];
    }
    int s = v.x + v.y + v.z + v.w;
    __shared__ int sm[256];
    sm[t] = s;
    __syncthreads();
    for (int off = 128; off > 0; off >>= 1) {
        if (t < off) sm[t] += sm[t + off];
        __syncthreads();
    }
    if (t == 0) part[blockIdx.x] = sm[0];
}

// scan2 folded in: wave 0 of every block redundantly exclusive-scans the 49 partials.
__global__ __launch_bounds__(256) void scan23(const int* __restrict__ cnt, const int* __restrict__ part,
                                              int* __restrict__ rowstart, int* __restrict__ cursor) {
    __shared__ int sbase;
    int t = threadIdx.x;
    if (t < 64) {
        int v = (t < SCAN_NB) ? part[t] : 0;
        #pragma unroll
        for (int off = 1; off < 64; off <<= 1) {
            int u = __shfl_up(v, off);
            if (t >= off) v += u;
        }
        int ex = __shfl_up(v, 1);
        if (t == 0) ex = 0;
        if (t == (int)blockIdx.x) sbase = ex;
        if (blockIdx.x == 0 && t == 0) rowstart[NNODES] = ETOT;
    }
    int base = blockIdx.x * SCAN_CH + t * 4;
    int4 v = {0, 0, 0, 0};
    if (base + 3 < NNODES) v = *(const int4*)(cnt + base);
    else {
        if (base + 0 < NNODES) v.x = cnt[base + 0];
        if (base + 1 < NNODES) v.y = cnt[base + 1];
        if (base + 2 < NNODES) v.z = cnt[base + 2];
        if (base + 3 < NNODES) v.w = cnt[base + 3];
    }
    int s = v.x + v.y + v.z + v.w;
    __shared__ int sm[2][256];
    sm[0][t] = s;
    __syncthreads();
    int cur = 0;
    #pragma unroll
    for (int off = 1; off < 256; off <<= 1) {
        int nxt = cur ^ 1;
        int val = sm[cur][t];
        if (t >= off) val += sm[cur][t - off];
        sm[nxt][t] = val;
        __syncthreads();
        cur = nxt;
    }
    int p = sm[cur][t] - s + sbase;
    if (base + 0 < NNODES) { rowstart[base + 0] = p; cursor[base + 0] = p; } p += v.x;
    if (base + 1 < NNODES) { rowstart[base + 1] = p; cursor[base + 1] = p; } p += v.y;
    if (base + 2 < NNODES) { rowstart[base + 2] = p; cursor[base + 2] = p; } p += v.z;
    if (base + 3 < NNODES) { rowstart[base + 3] = p; cursor[base + 3] = p; }
}

__global__ __launch_bounds__(256) void csr_fill(const int* __restrict__ ei,
                                                int* __restrict__ cursor,
                                                int* __restrict__ esrc) {
    int e = blockIdx.x * blockDim.x + threadIdx.x;
    if (e >= ETOT) return;
    int src, dst; edge_src_dst(ei, e, src, dst);
    int pos = atomicAdd(&cursor[dst], 1);
    esrc[pos] = src;
}

// ================= conv1 FUSED: gather x (both heads) + W1 GEMM + bias + att2 ====
// 16 nodes/block (grid 3125, exact). Phase 1: per-16-lane-group register softmax
// (deg<=32 2-slot path, rare deg>32 fallback) aggregates x into acc regs. Tile
// stored to LDS [16][264] (stride 264 -> 2-way bank alias, free). Phase 2: 4 waves
// x 16 MFMA compute C[16][256] = A @ W1 (block-diag heads), epilogue adds bias,
// writes xcat[:, :256] and computes conv2 att dots via U2 (atomicAdd per row).
// launch_bounds (256,8): R6 A/B showed the occupancy hint alone lifts 53->63%+;
// 36 VGPR < 64-cap, LDS 11.5KB x 8 = 92KB < 160KB.
__global__ __launch_bounds__(256, 8) void gat_conv1_fused(
    const int* __restrict__ rowstart, const int* __restrict__ esrc,
    const unsigned short* __restrict__ xb, const float* __restrict__ a_src,
    const float* __restrict__ a_dst, const unsigned short* __restrict__ W1t,
    const float* __restrict__ bias1, const float* __restrict__ U2,
    unsigned short* __restrict__ xcat, float* __restrict__ as2, float* __restrict__ ad2)
{
    __shared__ __attribute__((aligned(16))) unsigned short Alds[16 * 264];
    __shared__ float U2s[512];
    __shared__ float Bs[256];

    int tid = threadIdx.x;
    int t = tid & 15;
    int g = tid >> 4;                 // node group 0..15
    int nb = blockIdx.x * 16;
    int n = nb + g;                   // always < NNODES (50000 = 3125*16)

    U2s[tid] = U2[tid];
    U2s[tid + 256] = U2[tid + 256];
    Bs[tid] = bias1[tid];

    // ---- phase 1: gather ----
    int beg = rowstart[n], deg = rowstart[n + 1] - beg;
    const float2 adv = *(const float2*)(a_dst + (size_t)n * 2);
    float acc0[8] = {}, acc1[8] = {};

    if (deg <= 32) {
        int sa = 0, sb = 0;
        float la0 = -1e30f, la1 = -1e30f;
        float lb0 = -1e30f, lb1 = -1e30f;
        if (t < deg) {
            sa = esrc[beg + t];
            const float2 asv = *(const float2*)(a_src + (size_t)sa * 2);
            la0 = asv.x + adv.x; la0 = la0 >= 0.f ? la0 : 0.2f * la0;
            lb0 = asv.y + adv.y; lb0 = lb0 >= 0.f ? lb0 : 0.2f * lb0;
        }
        if (t + 16 < deg) {
            sb = esrc[beg + 16 + t];
            const float2 asv = *(const float2*)(a_src + (size_t)sb * 2);
            la1 = asv.x + adv.x; la1 = la1 >= 0.f ? la1 : 0.2f * la1;
            lb1 = asv.y + adv.y; lb1 = lb1 >= 0.f ? lb1 : 0.2f * lb1;
        }
        float m0 = fmaxf(la0, la1), m1 = fmaxf(lb0, lb1);
        #pragma unroll
        for (int off = 1; off < 16; off <<= 1) {
            m0 = fmaxf(m0, __shfl_xor(m0, off, 16));
            m1 = fmaxf(m1, __shfl_xor(m1, off, 16));
        }
        float ea0 = (t < deg)      ? __expf(la0 - m0) : 0.f;
        float ea1 = (t + 16 < deg) ? __expf(la1 - m0) : 0.f;
        float eb0 = (t < deg)      ? __expf(lb0 - m1) : 0.f;
        float eb1 = (t + 16 < deg) ? __expf(lb1 - m1) : 0.f;
        float s0 = ea0 + ea1, s1 = eb0 + eb1;
        #pragma unroll
        for (int off = 1; off < 16; off <<= 1) {
            s0 += __shfl_xor(s0, off, 16);
            s1 += __shfl_xor(s1, off, 16);
        }
        float i0 = 1.f / (s0 + 1e-16f), i1 = 1.f / (s1 + 1e-16f);
        float wa0 = ea0 * i0, wa1 = ea1 * i0;
        float wb0 = eb0 * i1, wb1 = eb1 * i1;

        int e = 0;
        for (; e + 3 < deg; e += 4) {
            int sx[4]; float w0x[4], w1x[4];
            #pragma unroll
            for (int u = 0; u < 4; ++u) {
                int ee = e + u;
                int hi = ee & 16, ln = ee & 15;
                sx[u]  = __shfl(hi ? sb  : sa,  ln, 16);
                w0x[u] = __shfl(hi ? wa1 : wa0, ln, 16);
                w1x[u] = __shfl(hi ? wb1 : wb0, ln, 16);
            }
            ushort8v hv[4];
            #pragma unroll
            for (int u = 0; u < 4; ++u)
                hv[u] = *(const ushort8v*)(xb + (size_t)sx[u] * 128 + t * 8);
            #pragma unroll
            for (int u = 0; u < 4; ++u) {
                #pragma unroll
                for (int j = 0; j < 8; ++j) {
                    float f = bf2f(hv[u][j]);
                    acc0[j] += w0x[u] * f;
                    acc1[j] += w1x[u] * f;
                }
            }
        }
        for (; e < deg; ++e) {
            int hi = e & 16, ln = e & 15;
            int   sX  = __shfl(hi ? sb  : sa,  ln, 16);
            float wX0 = __shfl(hi ? wa1 : wa0, ln, 16);
            float wX1 = __shfl(hi ? wb1 : wb0, ln, 16);
            const ushort8v hv = *(const ushort8v*)(xb + (size_t)sX * 128 + t * 8);
            #pragma unroll
            for (int j = 0; j < 8; ++j) {
                float f = bf2f(hv[j]);
                acc0[j] += wX0 * f; acc1[j] += wX1 * f;
            }
        }
    } else {
        // rare fallback (P[Pois(10)>31] ~ 2e-9)
        float m0 = -1e30f, m1 = -1e30f;
        for (int idx = t; idx < deg; idx += 16) {
            int s = esrc[beg + idx];
            const float2 asv = *(const float2*)(a_src + (size_t)s * 2);
            float l0 = asv.x + adv.x; l0 = l0 >= 0.f ? l0 : 0.2f * l0;
            float l1 = asv.y + adv.y; l1 = l1 >= 0.f ? l1 : 0.2f * l1;
            m0 = fmaxf(m0, l0); m1 = fmaxf(m1, l1);
        }
        #pragma unroll
        for (int off = 1; off < 16; off <<= 1) {
            m0 = fmaxf(m0, __shfl_xor(m0, off, 16));
            m1 = fmaxf(m1, __shfl_xor(m1, off, 16));
        }
        float s0 = 0.f, s1 = 0.f;
        for (int idx = t; idx < deg; idx += 16) {
            int s = esrc[beg + idx];
            const float2 asv = *(const float2*)(a_src + (size_t)s * 2);
            float l0 = asv.x + adv.x; l0 = l0 >= 0.f ? l0 : 0.2f * l0;
            float l1 = asv.y + adv.y; l1 = l1 >= 0.f ? l1 : 0.2f * l1;
            s0 += __expf(l0 - m0); s1 += __expf(l1 - m1);
        }
        #pragma unroll
        for (int off = 1; off < 16; off <<= 1) {
            s0 += __shfl_xor(s0, off, 16);
            s1 += __shfl_xor(s1, off, 16);
        }
        float inv0 = 1.f / (s0 + 1e-16f), inv1 = 1.f / (s1 + 1e-16f);
        for (int e = 0; e < deg; ++e) {
            int s = esrc[beg + e];
            const float2 asv = *(const float2*)(a_src + (size_t)s * 2);
            float l0 = asv.x + adv.x; l0 = l0 >= 0.f ? l0 : 0.2f * l0;
            float l1 = asv.y + adv.y; l1 = l1 >= 0.f ? l1 : 0.2f * l1;
            float w0 = __expf(l0 - m0) * inv0, w1 = __expf(l1 - m1) * inv1;
            const ushort8v hv = *(const ushort8v*)(xb + (size_t)s * 128 + t * 8);
            #pragma unroll
            for (int j = 0; j < 8; ++j) {
                float f = bf2f(hv[j]);
                acc0[j] += w0 * f; acc1[j] += w1 * f;
            }
        }
    }

    // store A-tile (bf16) : row g, head0 cols [t*8..), head1 cols [128+t*8..)
    {
        ushort8v o0, o1;
        #pragma unroll
        for (int j = 0; j < 8; ++j) { o0[j] = f2bf(acc0[j]); o1[j] = f2bf(acc1[j]); }
        *(ushort8v*)(Alds + g * 264 + t * 8) = o0;
        *(ushort8v*)(Alds + g * 264 + 128 + t * 8) = o1;
    }
    __syncthreads();

    // ---- phase 2: C[16][256] = A @ W1 (block-diag) ----
    int wave = tid >> 6, lane = tid & 63;
    int m = lane & 15, q = lane >> 4;
    int ncol0 = wave * 64;                 // output col base: 0,64 = head0; 128,192 = head1
    int kbase = (wave >= 2) ? 128 : 0;     // A K-columns for this head

    floatx4 cacc[4] = {};
    #pragma unroll
    for (int ks = 0; ks < 4; ++ks) {
        short8 a = *(const short8*)(Alds + m * 264 + kbase + ks * 32 + q * 8);
        #pragma unroll
        for (int ct = 0; ct < 4; ++ct) {
            short8 b = *(const short8*)(W1t + (size_t)(ncol0 + ct * 16 + m) * 128 + ks * 32 + q * 8);
            cacc[ct] = __builtin_amdgcn_mfma_f32_16x16x32_bf16(a, b, cacc[ct], 0, 0, 0);
        }
    }

    #pragma unroll
    for (int r = 0; r < 4; ++r) {
        int row = q * 4 + r;               // 0..15
        int gn = nb + row;
        float ds = 0.f, dd = 0.f;
        #pragma unroll
        for (int ct = 0; ct < 4; ++ct) {
            int col = ncol0 + ct * 16 + m;
            float vb = cacc[ct][r] + Bs[col];
            ds += vb * U2s[col];
            dd += vb * U2s[256 + col];
            xcat[(size_t)gn * 384 + col] = f2bf(vb);
        }
        #pragma unroll
        for (int off = 1; off < 16; off <<= 1) {
            ds += __shfl_xor(ds, off);
            dd += __shfl_xor(dd, off);
        }
        if (m == 0) {
            atomicAdd(&as2[gn], ds);
            atomicAdd(&ad2[gn], dd);
        }
    }
}

// conv2 (H=1, 128 feats): 2-slot register softmax (deg<=32), unroll-4 gathers.
__global__ __launch_bounds__(256, 8) void gat_gather_h1(
    const int* __restrict__ rowstart, const int* __restrict__ esrc,
    const unsigned short* __restrict__ hb, const float* __restrict__ a_src,
    const float* __restrict__ a_dst, const float* __restrict__ bias,
    unsigned short* __restrict__ xcat)
{
    int tid = threadIdx.x;
    int t = tid & 15;
    int g0 = (blockIdx.x * blockDim.x + tid) >> 4;
    int gstride = (gridDim.x * blockDim.x) >> 4;

    for (int n = g0; n < NNODES; n += gstride) {
        int beg = rowstart[n], deg = rowstart[n + 1] - beg;
        float ad0 = a_dst[n];
        float acc[8] = {};

        if (deg <= 32) {
            int sa = 0, sb = 0;
            float l0 = -1e30f, l1 = -1e30f;
            if (t < deg) {
                sa = esrc[beg + t];
                l0 = a_src[sa] + ad0; l0 = l0 >= 0.f ? l0 : 0.2f * l0;
            }
            if (t + 16 < deg) {
                sb = esrc[beg + 16 + t];
                l1 = a_src[sb] + ad0; l1 = l1 >= 0.f ? l1 : 0.2f * l1;
            }
            float m0 = fmaxf(l0, l1);
            #pragma unroll
            for (int off = 1; off < 16; off <<= 1)
                m0 = fmaxf(m0, __shfl_xor(m0, off, 16));
            float e0 = (t < deg)      ? __expf(l0 - m0) : 0.f;
            float e1 = (t + 16 < deg) ? __expf(l1 - m0) : 0.f;
            float s0 = e0 + e1;
            #pragma unroll
            for (int off = 1; off < 16; off <<= 1)
                s0 += __shfl_xor(s0, off, 16);
            float i0 = 1.f / (s0 + 1e-16f);
            float w0 = e0 * i0, w1 = e1 * i0;

            int e = 0;
            for (; e + 3 < deg; e += 4) {
                int sx[4]; float wx[4];
                #pragma unroll
                for (int u = 0; u < 4; ++u) {
                    int ee = e + u;
                    int hi = ee & 16, ln = ee & 15;
                    sx[u] = __shfl(hi ? sb : sa, ln, 16);
                    wx[u] = __shfl(hi ? w1 : w0, ln, 16);
                }
                ushort8v hv[4];
                #pragma unroll
                for (int u = 0; u < 4; ++u)
                    hv[u] = *(const ushort8v*)(hb + (size_t)sx[u] * 128 + t * 8);
                #pragma unroll
                for (int u = 0; u < 4; ++u) {
                    #pragma unroll
                    for (int j = 0; j < 8; ++j)
                        acc[j] += wx[u] * bf2f(hv[u][j]);
                }
            }
            for (; e < deg; ++e) {
                int hi = e & 16, ln = e & 15;
                int   sX = __shfl(hi ? sb : sa, ln, 16);
                float wX = __shfl(hi ? w1 : w0, ln, 16);
                const ushort8v hv = *(const ushort8v*)(hb + (size_t)sX * 128 + t * 8);
                #pragma unroll
                for (int j = 0; j < 8; ++j) acc[j] += wX * bf2f(hv[j]);
            }
        } else {
            float m0 = -1e30f;
            for (int idx = t; idx < deg; idx += 16) {
                int s = esrc[beg + idx];
                float l = a_src[s] + ad0; l = l >= 0.f ? l : 0.2f * l;
                m0 = fmaxf(m0, l);
            }
            #pragma unroll
            for (int off = 1; off < 16; off <<= 1)
                m0 = fmaxf(m0, __shfl_xor(m0, off, 16));
            float s0 = 0.f;
            for (int idx = t; idx < deg; idx += 16) {
                int s = esrc[beg + idx];
                float l = a_src[s] + ad0; l = l >= 0.f ? l : 0.2f * l;
                s0 += __expf(l - m0);
            }
            #pragma unroll
            for (int off = 1; off < 16; off <<= 1)
                s0 += __shfl_xor(s0, off, 16);
            float inv0 = 1.f / (s0 + 1e-16f);
            for (int e = 0; e < deg; ++e) {
                int s = esrc[beg + e];
                float l = a_src[s] + ad0; l = l >= 0.f ? l : 0.2f * l;
                float w = __expf(l - m0) * inv0;
                const ushort8v hv = *(const ushort8v*)(hb + (size_t)s * 128 + t * 8);
                #pragma unroll
                for (int j = 0; j < 8; ++j) acc[j] += w * bf2f(hv[j]);
            }
        }

        const float4 b0 = *(const float4*)(bias + t * 8);
        const float4 b1 = *(const float4*)(bias + t * 8 + 4);
        ushort8v o;
        o[0] = f2bf(acc[0] + b0.x); o[1] = f2bf(acc[1] + b0.y);
        o[2] = f2bf(acc[2] + b0.z); o[3] = f2bf(acc[3] + b0.w);
        o[4] = f2bf(acc[4] + b1.x); o[5] = f2bf(acc[5] + b1.y);
        o[6] = f2bf(acc[6] + b1.z); o[7] = f2bf(acc[7] + b1.w);
        *(ushort8v*)(xcat + (size_t)n * 384 + 256 + t * 8) = o;
    }
}

extern "C" void kernel_launch(void* const* d_in, const int* in_sizes, int n_in,
                              void* d_out, int out_size, void* d_ws, size_t ws_size,
                              hipStream_t stream) {
    const float* x        = (const float*)d_in[0];
    const int*   ei       = (const int*)d_in[1];
    const float* W1       = (const float*)d_in[2];
    const float* att_src1 = (const float*)d_in[3];
    const float* att_dst1 = (const float*)d_in[4];
    const float* bias1    = (const float*)d_in[5];
    const float* W2       = (const float*)d_in[6];
    const float* att_src2 = (const float*)d_in[7];
    const float* att_dst2 = (const float*)d_in[8];
    const float* bias2    = (const float*)d_in[9];
    const float* Wl       = (const float*)d_in[10];
    const float* bl       = (const float*)d_in[11];
    const float* gl       = (const float*)d_in[12];
    const float* betal    = (const float*)d_in[13];
    const float* Wa       = (const float*)d_in[14];
    const float* ba       = (const float*)d_in[15];
    const float* ga       = (const float*)d_in[16];
    const float* betaa    = (const float*)d_in[17];
    const float* Wb       = (const float*)d_in[18];
    const float* bb       = (const float*)d_in[19];
    const float* gb       = (const float*)d_in[20];
    const float* betab    = (const float*)d_in[21];
    float* out = (float*)d_out;
    char* ws = (char*)d_ws;

    const int N = NNODES;

    // ---------- workspace layout (bytes) ----------
    const size_t offY2b  = 0;            //  9.6 MB: y2b bf16 [50000][96]
    const size_t offXcat = 19200000;     // 38.4 MB: xcat bf16 [50000][384]
    const size_t offXb   = 57600000;     // 12.8 MB: xb bf16 -> hb2 bf16 [50000][128]
    const size_t offY1b  = 70400000;     //  9.6 MB: y1b bf16 [50000][96]
    const size_t offW1t  = 105600000;    // 64 KB
    const size_t offW2t  = 105665536;    // 64 KB
    const size_t offWlt  = 105731072;    // 96 KB
    const size_t offWat2 = 105829376;    // folded Wa bf16 [128][96]
    const size_t offWbt  = 105853952;    // folded Wb bf16 [64][96]
    const size_t offBaf  = 105866240;    // folded ba [96] f32
    const size_t offBbf  = 105866640;    // folded bb [2] f32
    const size_t offU1   = 105867264;    // U1 [512] f32 (W1-folded att vecs)
    const size_t offU2   = 105869312;    // U2 [512] f32 (W2-folded att vecs)
    const size_t offRow  = 106000000;    // cnt -> rowstart [N+1] ints
    const size_t offCur  = 106200128;    // cursor [N] ints
    const size_t offEsrc = 106400832;    // esrc [ETOT] ints
    const size_t offPart = 108700000;    // scan partials [64] ints
    const size_t offAs1  = 108800000;    // a_src1 [N*2] f32
    const size_t offAd1  = 109200000;
    const size_t offAs2  = 109600000;
    const size_t offAd2  = 109800000;
    const size_t offSt   = 110000000;    // stats

    unsigned short* y2b   = (unsigned short*)(ws + offY2b);
    unsigned short* xcat  = (unsigned short*)(ws + offXcat);
    unsigned short* xb    = (unsigned short*)(ws + offXb);
    unsigned short* hb2   = (unsigned short*)(ws + offXb);   // aliases xb: xb dead after conv1_fused
    unsigned short* y1b   = (unsigned short*)(ws + offY1b);
    unsigned short* W1t   = (unsigned short*)(ws + offW1t);
    unsigned short* W2t   = (unsigned short*)(ws + offW2t);
    unsigned short* Wlt   = (unsigned short*)(ws + offWlt);
    unsigned short* Wat2  = (unsigned short*)(ws + offWat2);
    unsigned short* Wbt   = (unsigned short*)(ws + offWbt);
    float* ba_f = (float*)(ws + offBaf);
    float* bb_f = (float*)(ws + offBbf);
    float* U1   = (float*)(ws + offU1);
    float* U2   = (float*)(ws + offU2);
    int* rowst  = (int*)(ws + offRow);
    int* cursor = (int*)(ws + offCur);
    int* esrc   = (int*)(ws + offEsrc);
    int* part   = (int*)(ws + offPart);
    float* as1  = (float*)(ws + offAs1);
    float* ad1  = (float*)(ws + offAd1);
    float* as2  = (float*)(ws + offAs2);
    float* ad2  = (float*)(ws + offAd2);

    float* csum_l = (float*)(ws + offSt + 0);
    float* csq_l  = (float*)(ws + offSt + 512);
    float* csum_a = (float*)(ws + offSt + 2048);
    float* csq_a  = (float*)(ws + offSt + 2560);
    float* csum_b = (float*)(ws + offSt + 4096);
    float* csq_b  = (float*)(ws + offSt + 4608);

    hipMemsetAsync(ws + offRow, 0, (NNODES + 1) * sizeof(int), stream);
    hipMemsetAsync(ws + offAs1, 0, (offSt + 6144) - offAs1, stream);

    dim3 blk(256);
    int edgeBlocks = (ETOT + 255) / 256;
    int gatherBlocks = 2048;             // 8192 waves, grid-stride (conv2 gather)
    dim3 gemmRows((N + GBM - 1) / GBM);

    // ---- fold att vectors + cast weights (merged); cast x fused with att1 dots ----
    fold_cast<<<512, blk, 0, stream>>>(W1, att_src1, att_dst1, W2, att_src2, att_dst2,
                                       Wl, U1, U2, W1t, W2t, Wlt);
    cast_x_att<<<(N + 7) / 8, blk, 0, stream>>>(x, U1, xb, as1, ad1);

    // ---- CSR build (scan2 folded into scan23) ----
    csr_count<<<edgeBlocks, blk, 0, stream>>>(ei, rowst);
    scan1<<<SCAN_NB, blk, 0, stream>>>(rowst, part);
    scan23<<<SCAN_NB, blk, 0, stream>>>(rowst, part, rowst, cursor);
    csr_fill<<<edgeBlocks, blk, 0, stream>>>(ei, cursor, esrc);

    // ---- conv1 fused: gather + per-head W1 MFMA + bias + conv2 att dots ----
    gat_conv1_fused<<<NNODES / 16, blk, 0, stream>>>(
        rowst, esrc, xb, as1, ad1, W1t, bias1, U2, xcat, as2, ad2);

    // ---- conv2: hb2 = bf16(xcat[:, :256] @ W2) ----
    gemm_mfma<<<dim3(2, gemmRows.x), blk, 0, stream>>>(
        xcat, 384, W2t, nullptr, hb2, 128, nullptr, nullptr, nullptr,
        N, 128, 256, 0);
    gat_gather_h1<<<gatherBlocks, blk, 0, stream>>>(rowst, esrc, hb2, as2, ad2, bias2, xcat);

    // ---- lin1: y1b = bf16(relu(xcat @ Wl + bl)), stats; fold BN into Wa ----
    gemm_mfma<<<dim3(2, gemmRows.x), blk, 0, stream>>>(
        xcat, 384, Wlt, nullptr, y1b, 96, bl, csum_l, csq_l,
        N, 96, 384, 1);
    bnfold_a<<<1, 256, 0, stream>>>(csum_l, csq_l, gl, betal, Wa, ba, Wat2, ba_f);

    // ---- mlp1 layer 1: y2b = bf16(relu(y1b @ Wa' + ba')), stats; fold BN into Wb ----
    gemm_mfma<<<dim3(2, gemmRows.x), blk, 0, stream>>>(
        y1b, 96, Wat2, nullptr, y2b, 96, ba_f, csum_a, csq_a,
        N, 96, 96, 1);
    bnfold_b<<<1, 256, 0, stream>>>(csum_a, csq_a, ga, betaa, Wb, bb, Wbt, bb_f);

    // ---- mlp1 layer 2: out = relu(y2b @ Wb' + bb'), stats (MFMA, N=2) ----
    gemm_mfma<<<dim3(1, gemmRows.x), blk, 0, stream>>>(
        y2b, 96, Wbt, out, nullptr, 2, bb_f, csum_b, csq_b,
        N, 2, 96, 1);

    // ---- final BN (fused finalize+apply) ----
    bn_fin_apply<<<(N * 2 + 255) / 256, blk, 0, stream>>>(csum_b, csq_b, gb, betab, out, N * 2);
}

// Round 9
// 340.984 us; speedup vs baseline: 1.0674x; 1.0602x over previous
//
#include <hip/hip_runtime.h>
#include <hip/hip_bf16.h>
#include <cstdint>
#include <cstddef>

#define NNODES 50000
#define NEDGES 500000
#define ETOT   (NEDGES + NNODES)

typedef __attribute__((ext_vector_type(8))) short short8;
typedef __attribute__((ext_vector_type(8))) unsigned short ushort8v;
typedef __attribute__((ext_vector_type(4))) float floatx4;
typedef __attribute__((ext_vector_type(4))) unsigned short ushort4v;

__device__ __forceinline__ unsigned short f2bf(float f) {
    union { __hip_bfloat16 h; unsigned short u; } cv;
    cv.h = __float2bfloat16(f);
    return cv.u;
}
__device__ __forceinline__ float bf2f(unsigned short u) {
    union { unsigned int i; float f; } cv;
    cv.i = ((unsigned int)u) << 16;
    return cv.f;
}

// ================= bf16 MFMA GEMM: C/Cb = op(A @ Bt^T + bias) =================
#define GBM 128
#define GBN 64
#define GBK 32

__global__ __launch_bounds__(256, 4) void gemm_mfma(
    const unsigned short* __restrict__ A, int lda,
    const unsigned short* __restrict__ Bt,
    float* __restrict__ C,
    unsigned short* __restrict__ Cb, int ldc,
    const float* __restrict__ bias,
    float* __restrict__ colsum, float* __restrict__ colsq,
    int M, int N, int K, int do_relu)
{
    __shared__ __attribute__((aligned(16))) unsigned short Alds[GBM * GBK];
    __shared__ __attribute__((aligned(16))) unsigned short Blds[GBN * GBK];
    __shared__ float scol[GBN], sqcol[GBN];

    int tid = threadIdx.x;
    int wave = tid >> 6, lane = tid & 63;
    int row0 = blockIdx.y * GBM;
    int col0 = blockIdx.x * GBN;
    int m = lane & 15, q = lane >> 4;

    floatx4 acc[2][4] = {};

    for (int k0 = 0; k0 < K; k0 += GBK) {
        #pragma unroll
        for (int i = 0; i < 2; ++i) {
            int c = tid + i * 256;
            int r = c >> 2, off = (c & 3) * 8;
            int gr = row0 + r;
            short8 v = {};
            if (gr < M) v = *(const short8*)(A + (size_t)gr * lda + k0 + off);
            *(short8*)(Alds + r * GBK + off) = v;
        }
        {
            int r = tid >> 2, off = (tid & 3) * 8;
            short8 v = *(const short8*)(Bt + (size_t)(col0 + r) * K + k0 + off);
            *(short8*)(Blds + r * GBK + off) = v;
        }
        __syncthreads();

        short8 a0 = *(const short8*)(Alds + (wave * 32 + m) * GBK + q * 8);
        short8 a1 = *(const short8*)(Alds + (wave * 32 + 16 + m) * GBK + q * 8);
        #pragma unroll
        for (int ct = 0; ct < 4; ++ct) {
            short8 b = *(const short8*)(Blds + (ct * 16 + m) * GBK + q * 8);
            acc[0][ct] = __builtin_amdgcn_mfma_f32_16x16x32_bf16(a0, b, acc[0][ct], 0, 0, 0);
            acc[1][ct] = __builtin_amdgcn_mfma_f32_16x16x32_bf16(a1, b, acc[1][ct], 0, 0, 0);
        }
        __syncthreads();
    }

    float ps[4] = {}, pq[4] = {};
    #pragma unroll
    for (int rt = 0; rt < 2; ++rt) {
        #pragma unroll
        for (int r = 0; r < 4; ++r) {
            int gr = row0 + wave * 32 + rt * 16 + q * 4 + r;
            #pragma unroll
            for (int ct = 0; ct < 4; ++ct) {
                int gc = col0 + ct * 16 + m;
                float v = acc[rt][ct][r];
                if (gc < N) {
                    float vb = v;
                    if (bias != nullptr) vb += bias[gc];
                    if (do_relu) vb = fmaxf(vb, 0.f);
                    if (gr < M) {
                        if (C  != nullptr) C[(size_t)gr * ldc + gc] = vb;
                        if (Cb != nullptr) Cb[(size_t)gr * ldc + gc] = f2bf(vb);
                        ps[ct] += vb; pq[ct] += vb * vb;
                    }
                }
            }
        }
    }
    if (colsum != nullptr) {
        if (tid < GBN) { scol[tid] = 0.f; sqcol[tid] = 0.f; }
        __syncthreads();
        #pragma unroll
        for (int ct = 0; ct < 4; ++ct) {
            atomicAdd(&scol[ct * 16 + m], ps[ct]);
            atomicAdd(&sqcol[ct * 16 + m], pq[ct]);
        }
        __syncthreads();
        if (tid < GBN) {
            int gc = col0 + tid;
            if (gc < N) {
                atomicAdd(&colsum[gc], scol[tid]);
                atomicAdd(&colsq[gc], sqcol[tid]);
            }
        }
    }
}

// ===== fold att vectors through W1/W2 + cast weights + zero-init (merged) ======
// Absorbs both hipMemsetAsync dispatches: zeroes rowstart[N+1], as2/ad2, stats.
// (as1/ad1/part/cursor are fully overwritten downstream - no zeroing needed.)
__global__ __launch_bounds__(256) void fold_cast_zero(
    const float* __restrict__ W1, const float* __restrict__ as1v, const float* __restrict__ ad1v,
    const float* __restrict__ W2, const float* __restrict__ as2v, const float* __restrict__ ad2v,
    const float* __restrict__ Wl,
    float* __restrict__ U1, float* __restrict__ U2,
    unsigned short* __restrict__ W1t, unsigned short* __restrict__ W2t,
    unsigned short* __restrict__ Wlt,
    int* __restrict__ rowst, float* __restrict__ as2z, float* __restrict__ statz)
{
    int z = blockIdx.x * 256 + threadIdx.x;       // 0..131071
    if (z <= NNODES) rowst[z] = 0;                // count/rowstart [N+1]
    if (z < 2 * NNODES) as2z[z] = 0.f;            // as2+ad2 (contiguous)
    if (z < 1536) statz[z] = 0.f;                 // col stats

    if (blockIdx.x < 64) {
        int g = threadIdx.x >> 5, l = threadIdx.x & 31;
        int task = blockIdx.x * 8 + g;   // 0..511
        float ss = 0.f, sd = 0.f;
        if (task < 256) {
            int d = task & 127, h = task >> 7;
            const float4 wv = *(const float4*)(W1 + d * 256 + h * 128 + l * 4);
            const float4 av = *(const float4*)(as1v + h * 128 + l * 4);
            const float4 bv = *(const float4*)(ad1v + h * 128 + l * 4);
            ss = wv.x * av.x + wv.y * av.y + wv.z * av.z + wv.w * av.w;
            sd = wv.x * bv.x + wv.y * bv.y + wv.z * bv.z + wv.w * bv.w;
        } else {
            int k = task - 256;
            const float4 wv = *(const float4*)(W2 + (size_t)k * 128 + l * 4);
            const float4 av = *(const float4*)(as2v + l * 4);
            const float4 bv = *(const float4*)(ad2v + l * 4);
            ss = wv.x * av.x + wv.y * av.y + wv.z * av.z + wv.w * av.w;
            sd = wv.x * bv.x + wv.y * bv.y + wv.z * bv.z + wv.w * bv.w;
        }
        #pragma unroll
        for (int off = 1; off < 32; off <<= 1) { ss += __shfl_xor(ss, off); sd += __shfl_xor(sd, off); }
        if (l == 0) {
            if (task < 256) {
                int d = task & 127, h = task >> 7;
                U1[h * 128 + d] = ss;
                U1[256 + h * 128 + d] = sd;
            } else {
                int k = task - 256;
                U2[k] = ss;
                U2[256 + k] = sd;
            }
        }
    } else {
        int i = (blockIdx.x - 64) * 256 + threadIdx.x;
        if (i < 32768) {                                   // W1t [256][128], W1 [128][256]
            int n = i >> 7, k = i & 127;
            W1t[i] = f2bf(W1[k * 256 + n]);
        } else if (i < 65536) {                            // W2t [128][256], W2 [256][128]
            int j = i - 32768;
            int n = j >> 8, k = j & 255;
            W2t[j] = f2bf(W2[k * 128 + n]);
        } else if (i < 114688) {                           // Wlt [128][384], Wl [384][96]
            int j = i - 65536;
            int n = j / 384, k = j % 384;
            Wlt[j] = (n < 96) ? f2bf(Wl[(size_t)k * 96 + n]) : (unsigned short)0;
        }
    }
}

__device__ __forceinline__ void edge_src_dst(const int* ei, int e, int& src, int& dst) {
    if (e < NEDGES) { src = ei[e]; dst = ei[NEDGES + e]; }
    else { src = e - NEDGES; dst = src; }
}

#define CASTB ((NNODES + 7) / 8)          // 6250
#define EDGEB ((ETOT + 255) / 256)        // 2149

// ===== merged: cast x -> bf16 + conv1 att dots (blocks < CASTB) || csr count ===
// Both halves depend only on fold_cast_zero and are mutually independent.
__global__ __launch_bounds__(256) void cast_csr(
    const float* __restrict__ x, const float* __restrict__ U1,
    unsigned short* __restrict__ xb, float* __restrict__ as1, float* __restrict__ ad1,
    const int* __restrict__ ei, int* __restrict__ cnt)
{
    __shared__ float Us[512];
    int tid = threadIdx.x;
    if (blockIdx.x < CASTB) {
        Us[tid] = U1[tid];
        Us[tid + 256] = U1[tid + 256];
        __syncthreads();
        int g = tid >> 5, l = tid & 31;
        int n = blockIdx.x * 8 + g;
        if (n >= NNODES) return;
        const float4 v = *(const float4*)(x + (size_t)n * 128 + l * 4);
        ushort4v o;
        o.x = f2bf(v.x); o.y = f2bf(v.y); o.z = f2bf(v.z); o.w = f2bf(v.w);
        *(ushort4v*)(xb + (size_t)n * 128 + l * 4) = o;
        const float4 us0 = *(const float4*)(Us + l * 4);
        const float4 us1 = *(const float4*)(Us + 128 + l * 4);
        const float4 ud0 = *(const float4*)(Us + 256 + l * 4);
        const float4 ud1 = *(const float4*)(Us + 384 + l * 4);
        float s0 = v.x * us0.x + v.y * us0.y + v.z * us0.z + v.w * us0.w;
        float s1 = v.x * us1.x + v.y * us1.y + v.z * us1.z + v.w * us1.w;
        float d0 = v.x * ud0.x + v.y * ud0.y + v.z * ud0.z + v.w * ud0.w;
        float d1 = v.x * ud1.x + v.y * ud1.y + v.z * ud1.z + v.w * ud1.w;
        #pragma unroll
        for (int off = 1; off < 32; off <<= 1) {
            s0 += __shfl_xor(s0, off); s1 += __shfl_xor(s1, off);
            d0 += __shfl_xor(d0, off); d1 += __shfl_xor(d1, off);
        }
        if (l == 0) {
            as1[n * 2] = s0; as1[n * 2 + 1] = s1;
            ad1[n * 2] = d0; ad1[n * 2 + 1] = d1;
        }
    } else {
        int e = (blockIdx.x - CASTB) * 256 + tid;
        if (e >= ETOT) return;
        int src, dst; edge_src_dst(ei, e, src, dst); (void)src;
        atomicAdd(&cnt[dst], 1);
    }
}

// ================= fused BN-finalize + weight-fold kernels =================
__global__ void bnfold_a(const float* __restrict__ csum, const float* __restrict__ csq,
                         const float* __restrict__ gamma, const float* __restrict__ beta,
                         const float* __restrict__ Wa, const float* __restrict__ ba,
                         unsigned short* __restrict__ Wat2, float* __restrict__ ba_f) {
    __shared__ float scl[96], shf[96];
    int tid = threadIdx.x;
    if (tid < 96) {
        float mu  = csum[tid] / (float)NNODES;
        float var = csq[tid] / (float)NNODES - mu * mu;
        if (var < 0.f) var = 0.f;
        float sc = gamma[tid] * rsqrtf(var + 1e-5f);
        scl[tid] = sc; shf[tid] = beta[tid] - mu * sc;
    }
    __syncthreads();
    for (int idx = tid; idx < 128 * 96; idx += 256) {
        int n = idx / 96, k = idx % 96;
        Wat2[idx] = (n < 96) ? f2bf(scl[k] * Wa[k * 96 + n]) : (unsigned short)0;
    }
    if (tid < 96) {
        float s = ba[tid];
        for (int k = 0; k < 96; ++k) s += shf[k] * Wa[k * 96 + tid];
        ba_f[tid] = s;
    }
}

__global__ void bnfold_b(const float* __restrict__ csum, const float* __restrict__ csq,
                         const float* __restrict__ gamma, const float* __restrict__ beta,
                         const float* __restrict__ Wb, const float* __restrict__ bb,
                         unsigned short* __restrict__ Wbt, float* __restrict__ bb_f) {
    __shared__ float scl[96], shf[96];
    int tid = threadIdx.x;
    if (tid < 96) {
        float mu  = csum[tid] / (float)NNODES;
        float var = csq[tid] / (float)NNODES - mu * mu;
        if (var < 0.f) var = 0.f;
        float sc = gamma[tid] * rsqrtf(var + 1e-5f);
        scl[tid] = sc; shf[tid] = beta[tid] - mu * sc;
    }
    __syncthreads();
    for (int idx = tid; idx < 64 * 96; idx += 256) {
        int n = idx / 96, k = idx % 96;
        Wbt[idx] = (n < 2) ? f2bf(scl[k] * Wb[k * 2 + n]) : (unsigned short)0;
    }
    if (tid < 2) {
        float s = bb[tid];
        for (int k = 0; k < 96; ++k) s += shf[k] * Wb[k * 2 + tid];
        bb_f[tid] = s;
    }
}

__global__ void bn_fin_apply(const float* __restrict__ csum, const float* __restrict__ csq,
                             const float* __restrict__ gamma, const float* __restrict__ beta,
                             float* __restrict__ y, int total) {
    int i = blockIdx.x * blockDim.x + threadIdx.x;
    if (i >= total) return;
    int j = i & 1;
    float mu  = csum[j] / (float)NNODES;
    float var = csq[j] / (float)NNODES - mu * mu;
    if (var < 0.f) var = 0.f;
    float sc = gamma[j] * rsqrtf(var + 1e-5f);
    float sh = beta[j] - mu * sc;
    y[i] = y[i] * sc + sh;
}

// ================= CSR build =================
#define SCAN_CH 1024
#define SCAN_NB ((NNODES + SCAN_CH - 1) / SCAN_CH)   // 49

__global__ __launch_bounds__(256) void scan1(const int* __restrict__ cnt, int* __restrict__ part) {
    int t = threadIdx.x;
    int base = blockIdx.x * SCAN_CH + t * 4;
    int4 v = {0, 0, 0, 0};
    if (base + 3 < NNODES) v = *(const int4*)(cnt + base);
    else {
        if (base + 0 < NNODES) v.x = cnt[base + 0];
        if (base + 1 < NNODES) v.y = cnt[base + 1];
        if (base + 2 < NNODES) v.z = cnt[base + 2];
        if (base + 3 < NNODES) v.w = cnt[base + 3];
    }
    int s = v.x + v.y + v.z + v.w;
    __shared__ int sm[256];
    sm[t] = s;
    __syncthreads();
    for (int off = 128; off > 0; off >>= 1) {
        if (t < off) sm[t] += sm[t + off];
        __syncthreads();
    }
    if (t == 0) part[blockIdx.x] = sm[0];
}

// scan2 folded in: wave 0 of every block redundantly exclusive-scans the 49 partials.
__global__ __launch_bounds__(256) void scan23(const int* __restrict__ cnt, const int* __restrict__ part,
                                              int* __restrict__ rowstart, int* __restrict__ cursor) {
    __shared__ int sbase;
    int t = threadIdx.x;
    if (t < 64) {
        int v = (t < SCAN_NB) ? part[t] : 0;
        #pragma unroll
        for (int off = 1; off < 64; off <<= 1) {
            int u = __shfl_up(v, off);
            if (t >= off) v += u;
        }
        int ex = __shfl_up(v, 1);
        if (t == 0) ex = 0;
        if (t == (int)blockIdx.x) sbase = ex;
        if (blockIdx.x == 0 && t == 0) rowstart[NNODES] = ETOT;
    }
    int base = blockIdx.x * SCAN_CH + t * 4;
    int4 v = {0, 0, 0, 0};
    if (base + 3 < NNODES) v = *(const int4*)(cnt + base);
    else {
        if (base + 0 < NNODES) v.x = cnt[base + 0];
        if (base + 1 < NNODES) v.y = cnt[base + 1];
        if (base + 2 < NNODES) v.z = cnt[base + 2];
        if (base + 3 < NNODES) v.w = cnt[base + 3];
    }
    int s = v.x + v.y + v.z + v.w;
    __shared__ int sm[2][256];
    sm[0][t] = s;
    __syncthreads();
    int cur = 0;
    #pragma unroll
    for (int off = 1; off < 256; off <<= 1) {
        int nxt = cur ^ 1;
        int val = sm[cur][t];
        if (t >= off) val += sm[cur][t - off];
        sm[nxt][t] = val;
        __syncthreads();
        cur = nxt;
    }
    int p = sm[cur][t] - s + sbase;
    if (base + 0 < NNODES) { rowstart[base + 0] = p; cursor[base + 0] = p; } p += v.x;
    if (base + 1 < NNODES) { rowstart[base + 1] = p; cursor[base + 1] = p; } p += v.y;
    if (base + 2 < NNODES) { rowstart[base + 2] = p; cursor[base + 2] = p; } p += v.z;
    if (base + 3 < NNODES) { rowstart[base + 3] = p; cursor[base + 3] = p; }
}

__global__ __launch_bounds__(256) void csr_fill(const int* __restrict__ ei,
                                                int* __restrict__ cursor,
                                                int* __restrict__ esrc) {
    int e = blockIdx.x * blockDim.x + threadIdx.x;
    if (e >= ETOT) return;
    int src, dst; edge_src_dst(ei, e, src, dst);
    int pos = atomicAdd(&cursor[dst], 1);
    esrc[pos] = src;
}

// ================= conv1 FUSED: gather x (both heads) + W1 GEMM + bias + att2 ====
// Identical body to R5 (measured 54.3 us). 16 nodes/block, grid 3125 exact.
__global__ __launch_bounds__(256, 4) void gat_conv1_fused(
    const int* __restrict__ rowstart, const int* __restrict__ esrc,
    const unsigned short* __restrict__ xb, const float* __restrict__ a_src,
    const float* __restrict__ a_dst, const unsigned short* __restrict__ W1t,
    const float* __restrict__ bias1, const float* __restrict__ U2,
    unsigned short* __restrict__ xcat, float* __restrict__ as2, float* __restrict__ ad2)
{
    __shared__ __attribute__((aligned(16))) unsigned short Alds[16 * 264];
    __shared__ float U2s[512];
    __shared__ float Bs[256];

    int tid = threadIdx.x;
    int t = tid & 15;
    int g = tid >> 4;
    int nb = blockIdx.x * 16;
    int n = nb + g;

    U2s[tid] = U2[tid];
    U2s[tid + 256] = U2[tid + 256];
    Bs[tid] = bias1[tid];

    int beg = rowstart[n], deg = rowstart[n + 1] - beg;
    const float2 adv = *(const float2*)(a_dst + (size_t)n * 2);
    float acc0[8] = {}, acc1[8] = {};

    if (deg <= 32) {
        int sa = 0, sb = 0;
        float la0 = -1e30f, la1 = -1e30f;
        float lb0 = -1e30f, lb1 = -1e30f;
        if (t < deg) {
            sa = esrc[beg + t];
            const float2 asv = *(const float2*)(a_src + (size_t)sa * 2);
            la0 = asv.x + adv.x; la0 = la0 >= 0.f ? la0 : 0.2f * la0;
            lb0 = asv.y + adv.y; lb0 = lb0 >= 0.f ? lb0 : 0.2f * lb0;
        }
        if (t + 16 < deg) {
            sb = esrc[beg + 16 + t];
            const float2 asv = *(const float2*)(a_src + (size_t)sb * 2);
            la1 = asv.x + adv.x; la1 = la1 >= 0.f ? la1 : 0.2f * la1;
            lb1 = asv.y + adv.y; lb1 = lb1 >= 0.f ? lb1 : 0.2f * lb1;
        }
        float m0 = fmaxf(la0, la1), m1 = fmaxf(lb0, lb1);
        #pragma unroll
        for (int off = 1; off < 16; off <<= 1) {
            m0 = fmaxf(m0, __shfl_xor(m0, off, 16));
            m1 = fmaxf(m1, __shfl_xor(m1, off, 16));
        }
        float ea0 = (t < deg)      ? __expf(la0 - m0) : 0.f;
        float ea1 = (t + 16 < deg) ? __expf(la1 - m0) : 0.f;
        float eb0 = (t < deg)      ? __expf(lb0 - m1) : 0.f;
        float eb1 = (t + 16 < deg) ? __expf(lb1 - m1) : 0.f;
        float s0 = ea0 + ea1, s1 = eb0 + eb1;
        #pragma unroll
        for (int off = 1; off < 16; off <<= 1) {
            s0 += __shfl_xor(s0, off, 16);
            s1 += __shfl_xor(s1, off, 16);
        }
        float i0 = 1.f / (s0 + 1e-16f), i1 = 1.f / (s1 + 1e-16f);
        float wa0 = ea0 * i0, wa1 = ea1 * i0;
        float wb0 = eb0 * i1, wb1 = eb1 * i1;

        int e = 0;
        for (; e + 3 < deg; e += 4) {
            int sx[4]; float w0x[4], w1x[4];
            #pragma unroll
            for (int u = 0; u < 4; ++u) {
                int ee = e + u;
                int hi = ee & 16, ln = ee & 15;
                sx[u]  = __shfl(hi ? sb  : sa,  ln, 16);
                w0x[u] = __shfl(hi ? wa1 : wa0, ln, 16);
                w1x[u] = __shfl(hi ? wb1 : wb0, ln, 16);
            }
            ushort8v hv[4];
            #pragma unroll
            for (int u = 0; u < 4; ++u)
                hv[u] = *(const ushort8v*)(xb + (size_t)sx[u] * 128 + t * 8);
            #pragma unroll
            for (int u = 0; u < 4; ++u) {
                #pragma unroll
                for (int j = 0; j < 8; ++j) {
                    float f = bf2f(hv[u][j]);
                    acc0[j] += w0x[u] * f;
                    acc1[j] += w1x[u] * f;
                }
            }
        }
        for (; e < deg; ++e) {
            int hi = e & 16, ln = e & 15;
            int   sX  = __shfl(hi ? sb  : sa,  ln, 16);
            float wX0 = __shfl(hi ? wa1 : wa0, ln, 16);
            float wX1 = __shfl(hi ? wb1 : wb0, ln, 16);
            const ushort8v hv = *(const ushort8v*)(xb + (size_t)sX * 128 + t * 8);
            #pragma unroll
            for (int j = 0; j < 8; ++j) {
                float f = bf2f(hv[j]);
                acc0[j] += wX0 * f; acc1[j] += wX1 * f;
            }
        }
    } else {
        float m0 = -1e30f, m1 = -1e30f;
        for (int idx = t; idx < deg; idx += 16) {
            int s = esrc[beg + idx];
            const float2 asv = *(const float2*)(a_src + (size_t)s * 2);
            float l0 = asv.x + adv.x; l0 = l0 >= 0.f ? l0 : 0.2f * l0;
            float l1 = asv.y + adv.y; l1 = l1 >= 0.f ? l1 : 0.2f * l1;
            m0 = fmaxf(m0, l0); m1 = fmaxf(m1, l1);
        }
        #pragma unroll
        for (int off = 1; off < 16; off <<= 1) {
            m0 = fmaxf(m0, __shfl_xor(m0, off, 16));
            m1 = fmaxf(m1, __shfl_xor(m1, off, 16));
        }
        float s0 = 0.f, s1 = 0.f;
        for (int idx = t; idx < deg; idx += 16) {
            int s = esrc[beg + idx];
            const float2 asv = *(const float2*)(a_src + (size_t)s * 2);
            float l0 = asv.x + adv.x; l0 = l0 >= 0.f ? l0 : 0.2f * l0;
            float l1 = asv.y + adv.y; l1 = l1 >= 0.f ? l1 : 0.2f * l1;
            s0 += __expf(l0 - m0); s1 += __expf(l1 - m1);
        }
        #pragma unroll
        for (int off = 1; off < 16; off <<= 1) {
            s0 += __shfl_xor(s0, off, 16);
            s1 += __shfl_xor(s1, off, 16);
        }
        float inv0 = 1.f / (s0 + 1e-16f), inv1 = 1.f / (s1 + 1e-16f);
        for (int e = 0; e < deg; ++e) {
            int s = esrc[beg + e];
            const float2 asv = *(const float2*)(a_src + (size_t)s * 2);
            float l0 = asv.x + adv.x; l0 = l0 >= 0.f ? l0 : 0.2f * l0;
            float l1 = asv.y + adv.y; l1 = l1 >= 0.f ? l1 : 0.2f * l1;
            float w0 = __expf(l0 - m0) * inv0, w1 = __expf(l1 - m1) * inv1;
            const ushort8v hv = *(const ushort8v*)(xb + (size_t)s * 128 + t * 8);
            #pragma unroll
            for (int j = 0; j < 8; ++j) {
                float f = bf2f(hv[j]);
                acc0[j] += w0 * f; acc1[j] += w1 * f;
            }
        }
    }

    {
        ushort8v o0, o1;
        #pragma unroll
        for (int j = 0; j < 8; ++j) { o0[j] = f2bf(acc0[j]); o1[j] = f2bf(acc1[j]); }
        *(ushort8v*)(Alds + g * 264 + t * 8) = o0;
        *(ushort8v*)(Alds + g * 264 + 128 + t * 8) = o1;
    }
    __syncthreads();

    int wave = tid >> 6, lane = tid & 63;
    int m = lane & 15, q = lane >> 4;
    int ncol0 = wave * 64;
    int kbase = (wave >= 2) ? 128 : 0;

    floatx4 cacc[4] = {};
    #pragma unroll
    for (int ks = 0; ks < 4; ++ks) {
        short8 a = *(const short8*)(Alds + m * 264 + kbase + ks * 32 + q * 8);
        #pragma unroll
        for (int ct = 0; ct < 4; ++ct) {
            short8 b = *(const short8*)(W1t + (size_t)(ncol0 + ct * 16 + m) * 128 + ks * 32 + q * 8);
            cacc[ct] = __builtin_amdgcn_mfma_f32_16x16x32_bf16(a, b, cacc[ct], 0, 0, 0);
        }
    }

    #pragma unroll
    for (int r = 0; r < 4; ++r) {
        int row = q * 4 + r;
        int gn = nb + row;
        float ds = 0.f, dd = 0.f;
        #pragma unroll
        for (int ct = 0; ct < 4; ++ct) {
            int col = ncol0 + ct * 16 + m;
            float vb = cacc[ct][r] + Bs[col];
            ds += vb * U2s[col];
            dd += vb * U2s[256 + col];
            xcat[(size_t)gn * 384 + col] = f2bf(vb);
        }
        #pragma unroll
        for (int off = 1; off < 16; off <<= 1) {
            ds += __shfl_xor(ds, off);
            dd += __shfl_xor(dd, off);
        }
        if (m == 0) {
            atomicAdd(&as2[gn], ds);
            atomicAdd(&ad2[gn], dd);
        }
    }
}

// conv2 (H=1, 128 feats): 2-slot register softmax (deg<=32), unroll-4 gathers.
__global__ __launch_bounds__(256) void gat_gather_h1(
    const int* __restrict__ rowstart, const int* __restrict__ esrc,
    const unsigned short* __restrict__ hb, const float* __restrict__ a_src,
    const float* __restrict__ a_dst, const float* __restrict__ bias,
    unsigned short* __restrict__ xcat)
{
    int tid = threadIdx.x;
    int t = tid & 15;
    int g0 = (blockIdx.x * blockDim.x + tid) >> 4;
    int gstride = (gridDim.x * blockDim.x) >> 4;

    for (int n = g0; n < NNODES; n += gstride) {
        int beg = rowstart[n], deg = rowstart[n + 1] - beg;
        float ad0 = a_dst[n];
        float acc[8] = {};

        if (deg <= 32) {
            int sa = 0, sb = 0;
            float l0 = -1e30f, l1 = -1e30f;
            if (t < deg) {
                sa = esrc[beg + t];
                l0 = a_src[sa] + ad0; l0 = l0 >= 0.f ? l0 : 0.2f * l0;
            }
            if (t + 16 < deg) {
                sb = esrc[beg + 16 + t];
                l1 = a_src[sb] + ad0; l1 = l1 >= 0.f ? l1 : 0.2f * l1;
            }
            float m0 = fmaxf(l0, l1);
            #pragma unroll
            for (int off = 1; off < 16; off <<= 1)
                m0 = fmaxf(m0, __shfl_xor(m0, off, 16));
            float e0 = (t < deg)      ? __expf(l0 - m0) : 0.f;
            float e1 = (t + 16 < deg) ? __expf(l1 - m0) : 0.f;
            float s0 = e0 + e1;
            #pragma unroll
            for (int off = 1; off < 16; off <<= 1)
                s0 += __shfl_xor(s0, off, 16);
            float i0 = 1.f / (s0 + 1e-16f);
            float w0 = e0 * i0, w1 = e1 * i0;

            int e = 0;
            for (; e + 3 < deg; e += 4) {
                int sx[4]; float wx[4];
                #pragma unroll
                for (int u = 0; u < 4; ++u) {
                    int ee = e + u;
                    int hi = ee & 16, ln = ee & 15;
                    sx[u] = __shfl(hi ? sb : sa, ln, 16);
                    wx[u] = __shfl(hi ? w1 : w0, ln, 16);
                }
                ushort8v hv[4];
                #pragma unroll
                for (int u = 0; u < 4; ++u)
                    hv[u] = *(const ushort8v*)(hb + (size_t)sx[u] * 128 + t * 8);
                #pragma unroll
                for (int u = 0; u < 4; ++u) {
                    #pragma unroll
                    for (int j = 0; j < 8; ++j)
                        acc[j] += wx[u] * bf2f(hv[u][j]);
                }
            }
            for (; e < deg; ++e) {
                int hi = e & 16, ln = e & 15;
                int   sX = __shfl(hi ? sb : sa, ln, 16);
                float wX = __shfl(hi ? w1 : w0, ln, 16);
                const ushort8v hv = *(const ushort8v*)(hb + (size_t)sX * 128 + t * 8);
                #pragma unroll
                for (int j = 0; j < 8; ++j) acc[j] += wX * bf2f(hv[j]);
            }
        } else {
            float m0 = -1e30f;
            for (int idx = t; idx < deg; idx += 16) {
                int s = esrc[beg + idx];
                float l = a_src[s] + ad0; l = l >= 0.f ? l : 0.2f * l;
                m0 = fmaxf(m0, l);
            }
            #pragma unroll
            for (int off = 1; off < 16; off <<= 1)
                m0 = fmaxf(m0, __shfl_xor(m0, off, 16));
            float s0 = 0.f;
            for (int idx = t; idx < deg; idx += 16) {
                int s = esrc[beg + idx];
                float l = a_src[s] + ad0; l = l >= 0.f ? l : 0.2f * l;
                s0 += __expf(l - m0);
            }
            #pragma unroll
            for (int off = 1; off < 16; off <<= 1)
                s0 += __shfl_xor(s0, off, 16);
            float inv0 = 1.f / (s0 + 1e-16f);
            for (int e = 0; e < deg; ++e) {
                int s = esrc[beg + e];
                float l = a_src[s] + ad0; l = l >= 0.f ? l : 0.2f * l;
                float w = __expf(l - m0) * inv0;
                const ushort8v hv = *(const ushort8v*)(hb + (size_t)s * 128 + t * 8);
                #pragma unroll
                for (int j = 0; j < 8; ++j) acc[j] += w * bf2f(hv[j]);
            }
        }

        const float4 b0 = *(const float4*)(bias + t * 8);
        const float4 b1 = *(const float4*)(bias + t * 8 + 4);
        ushort8v o;
        o[0] = f2bf(acc[0] + b0.x); o[1] = f2bf(acc[1] + b0.y);
        o[2] = f2bf(acc[2] + b0.z); o[3] = f2bf(acc[3] + b0.w);
        o[4] = f2bf(acc[4] + b1.x); o[5] = f2bf(acc[5] + b1.y);
        o[6] = f2bf(acc[6] + b1.z); o[7] = f2bf(acc[7] + b1.w);
        *(ushort8v*)(xcat + (size_t)n * 384 + 256 + t * 8) = o;
    }
}

extern "C" void kernel_launch(void* const* d_in, const int* in_sizes, int n_in,
                              void* d_out, int out_size, void* d_ws, size_t ws_size,
                              hipStream_t stream) {
    const float* x        = (const float*)d_in[0];
    const int*   ei       = (const int*)d_in[1];
    const float* W1       = (const float*)d_in[2];
    const float* att_src1 = (const float*)d_in[3];
    const float* att_dst1 = (const float*)d_in[4];
    const float* bias1    = (const float*)d_in[5];
    const float* W2       = (const float*)d_in[6];
    const float* att_src2 = (const float*)d_in[7];
    const float* att_dst2 = (const float*)d_in[8];
    const float* bias2    = (const float*)d_in[9];
    const float* Wl       = (const float*)d_in[10];
    const float* bl       = (const float*)d_in[11];
    const float* gl       = (const float*)d_in[12];
    const float* betal    = (const float*)d_in[13];
    const float* Wa       = (const float*)d_in[14];
    const float* ba       = (const float*)d_in[15];
    const float* ga       = (const float*)d_in[16];
    const float* betaa    = (const float*)d_in[17];
    const float* Wb       = (const float*)d_in[18];
    const float* bb       = (const float*)d_in[19];
    const float* gb       = (const float*)d_in[20];
    const float* betab    = (const float*)d_in[21];
    float* out = (float*)d_out;
    char* ws = (char*)d_ws;

    const int N = NNODES;

    // ---------- workspace layout (bytes) ----------
    const size_t offY2b  = 0;            //  9.6 MB: y2b bf16 [50000][96]
    const size_t offXcat = 19200000;     // 38.4 MB: xcat bf16 [50000][384]
    const size_t offXb   = 57600000;     // 12.8 MB: xb bf16 -> hb2 bf16 [50000][128]
    const size_t offY1b  = 70400000;     //  9.6 MB: y1b bf16 [50000][96]
    const size_t offW1t  = 105600000;    // 64 KB
    const size_t offW2t  = 105665536;    // 64 KB
    const size_t offWlt  = 105731072;    // 96 KB
    const size_t offWat2 = 105829376;    // folded Wa bf16 [128][96]
    const size_t offWbt  = 105853952;    // folded Wb bf16 [64][96]
    const size_t offBaf  = 105866240;    // folded ba [96] f32
    const size_t offBbf  = 105866640;    // folded bb [2] f32
    const size_t offU1   = 105867264;    // U1 [512] f32 (W1-folded att vecs)
    const size_t offU2   = 105869312;    // U2 [512] f32 (W2-folded att vecs)
    const size_t offRow  = 106000000;    // cnt -> rowstart [N+1] ints
    const size_t offCur  = 106200128;    // cursor [N] ints
    const size_t offEsrc = 106400832;    // esrc [ETOT] ints
    const size_t offPart = 108700000;    // scan partials [64] ints
    const size_t offAs1  = 108800000;    // a_src1 [N*2] f32
    const size_t offAd1  = 109200000;
    const size_t offAs2  = 109600000;    // as2 [N] f32 (ad2 contiguous after)
    const size_t offAd2  = 109800000;
    const size_t offSt   = 110000000;    // stats

    unsigned short* y2b   = (unsigned short*)(ws + offY2b);
    unsigned short* xcat  = (unsigned short*)(ws + offXcat);
    unsigned short* xb    = (unsigned short*)(ws + offXb);
    unsigned short* hb2   = (unsigned short*)(ws + offXb);   // aliases xb: xb dead after conv1_fused
    unsigned short* y1b   = (unsigned short*)(ws + offY1b);
    unsigned short* W1t   = (unsigned short*)(ws + offW1t);
    unsigned short* W2t   = (unsigned short*)(ws + offW2t);
    unsigned short* Wlt   = (unsigned short*)(ws + offWlt);
    unsigned short* Wat2  = (unsigned short*)(ws + offWat2);
    unsigned short* Wbt   = (unsigned short*)(ws + offWbt);
    float* ba_f = (float*)(ws + offBaf);
    float* bb_f = (float*)(ws + offBbf);
    float* U1   = (float*)(ws + offU1);
    float* U2   = (float*)(ws + offU2);
    int* rowst  = (int*)(ws + offRow);
    int* cursor = (int*)(ws + offCur);
    int* esrc   = (int*)(ws + offEsrc);
    int* part   = (int*)(ws + offPart);
    float* as1  = (float*)(ws + offAs1);
    float* ad1  = (float*)(ws + offAd1);
    float* as2  = (float*)(ws + offAs2);
    float* ad2  = (float*)(ws + offAd2);
    float* statz = (float*)(ws + offSt);

    float* csum_l = (float*)(ws + offSt + 0);
    float* csq_l  = (float*)(ws + offSt + 512);
    float* csum_a = (float*)(ws + offSt + 2048);
    float* csq_a  = (float*)(ws + offSt + 2560);
    float* csum_b = (float*)(ws + offSt + 4096);
    float* csq_b  = (float*)(ws + offSt + 4608);

    dim3 blk(256);
    int gatherBlocks = 2048;             // 8192 waves, grid-stride (conv2 gather)
    dim3 gemmRows((N + GBM - 1) / GBM);

    // 1) fold att vectors + cast weights + zero-init (absorbs both memsets)
    fold_cast_zero<<<512, blk, 0, stream>>>(W1, att_src1, att_dst1, W2, att_src2, att_dst2,
                                            Wl, U1, U2, W1t, W2t, Wlt, rowst, as2, statz);

    // 2) cast x + conv1 att dots || csr count (merged, independent halves)
    cast_csr<<<CASTB + EDGEB, blk, 0, stream>>>(x, U1, xb, as1, ad1, ei, rowst);

    // 3-5) CSR scan + fill
    scan1<<<SCAN_NB, blk, 0, stream>>>(rowst, part);
    scan23<<<SCAN_NB, blk, 0, stream>>>(rowst, part, rowst, cursor);
    csr_fill<<<EDGEB, blk, 0, stream>>>(ei, cursor, esrc);

    // 6) conv1 fused: gather + per-head W1 MFMA + bias + conv2 att dots
    gat_conv1_fused<<<NNODES / 16, blk, 0, stream>>>(
        rowst, esrc, xb, as1, ad1, W1t, bias1, U2, xcat, as2, ad2);

    // 7) conv2: hb2 = bf16(xcat[:, :256] @ W2)
    gemm_mfma<<<dim3(2, gemmRows.x), blk, 0, stream>>>(
        xcat, 384, W2t, nullptr, hb2, 128, nullptr, nullptr, nullptr,
        N, 128, 256, 0);
    // 8) conv2 aggregation
    gat_gather_h1<<<gatherBlocks, blk, 0, stream>>>(rowst, esrc, hb2, as2, ad2, bias2, xcat);

    // 9) lin1: y1b = bf16(relu(xcat @ Wl + bl)), stats; 10) fold BN into Wa
    gemm_mfma<<<dim3(2, gemmRows.x), blk, 0, stream>>>(
        xcat, 384, Wlt, nullptr, y1b, 96, bl, csum_l, csq_l,
        N, 96, 384, 1);
    bnfold_a<<<1, 256, 0, stream>>>(csum_l, csq_l, gl, betal, Wa, ba, Wat2, ba_f);

    // 11) mlp1 layer 1; 12) fold BN into Wb
    gemm_mfma<<<dim3(2, gemmRows.x), blk, 0, stream>>>(
        y1b, 96, Wat2, nullptr, y2b, 96, ba_f, csum_a, csq_a,
        N, 96, 96, 1);
    bnfold_b<<<1, 256, 0, stream>>>(csum_a, csq_a, ga, betaa, Wb, bb, Wbt, bb_f);

    // 13) mlp1 layer 2: out = relu(y2b @ Wb' + bb'), stats (MFMA, N=2)
    gemm_mfma<<<dim3(1, gemmRows.x), blk, 0, stream>>>(
        y2b, 96, Wbt, out, nullptr, 2, bb_f, csum_b, csq_b,
        N, 2, 96, 1);

    // 14) final BN (fused finalize+apply)
    bn_fin_apply<<<(N * 2 + 255) / 256, blk, 0, stream>>>(csum_b, csq_b, gb, betab, out, N * 2);
}